// Round 7
// baseline (222.547 us; speedup 1.0000x reference)
//
#include <hip/hip_runtime.h>
#include <hip/hip_bf16.h>
#include <cmath>

// Problem constants (fixed by reference)
constexpr int Bb = 2;
constexpr int Ls = 2048;
constexpr int Dd = 1024;
constexpr int Hh = 16;
constexpr int DHh = 64;
constexpr int Rr = 32;
constexpr int BL = Bb * Ls;          // 4096
constexpr float LORA_SCALE = 2.0f;   // 64/32
constexpr float LN_EPS = 1e-5f;
constexpr float ATTN_SCALE = 0.125f; // 1/sqrt(64)
constexpr float LOG2E = 1.4426950408889634f;
constexpr float QSCL = ATTN_SCALE * LOG2E;  // folded into qt

typedef __attribute__((ext_vector_type(8))) short bf16x8;
typedef __attribute__((ext_vector_type(4))) float f32x4;

__device__ __forceinline__ unsigned short f2bf(float f) {
    __hip_bfloat16 b = __float2bfloat16(f);
    return *reinterpret_cast<unsigned short*>(&b);
}
__device__ __forceinline__ float bf2f(unsigned short u) {
    unsigned int x = ((unsigned int)u) << 16;
    return __uint_as_float(x);
}
__device__ __forceinline__ void async_copy16(const void* g, void* l) {
    __builtin_amdgcn_global_load_lds(
        (__attribute__((address_space(1))) void*)(void*)(size_t)g,
        (__attribute__((address_space(3))) void*)l, 16, 0, 0);
}

// ---------------- 0. fused prep: merge-wqkv | cast w_out | rope | ln_x --------
__global__ __launch_bounds__(256) void prep_ln_kernel(const float* __restrict__ w,
                                                      const float* __restrict__ qa,
                                                      const float* __restrict__ qb,
                                                      const float* __restrict__ va,
                                                      const float* __restrict__ vb,
                                                      const float* __restrict__ wout,
                                                      const float* __restrict__ x,
                                                      const float* __restrict__ lnw,
                                                      const float* __restrict__ lnb,
                                                      unsigned short* __restrict__ wqkvb,
                                                      unsigned short* __restrict__ woutb,
                                                      float* __restrict__ ropec,
                                                      float* __restrict__ ropes,
                                                      unsigned short* __restrict__ hb) {
    const int blk = blockIdx.x;
    const int tid = threadIdx.x;
    if (blk < 3 * Dd) {
        const int e = blk;
        const int d0 = tid * 4;
        __shared__ float br[Rr];
        const bool isq = (e < Dd);
        const bool isv = (e >= 2 * Dd);
        const float* bsrc = isq ? (qb + (size_t)e * Rr)
                                : (isv ? (vb + (size_t)(e - 2 * Dd) * Rr) : nullptr);
        const float* asrc = isq ? qa : va;
        if (bsrc && tid < Rr) br[tid] = bsrc[tid];
        __syncthreads();
        float acc[4] = {0.f, 0.f, 0.f, 0.f};
        if (bsrc) {
#pragma unroll 8
            for (int r = 0; r < Rr; ++r) {
                float4 av = *(const float4*)(asrc + (size_t)r * Dd + d0);
                acc[0] += br[r] * av.x; acc[1] += br[r] * av.y;
                acc[2] += br[r] * av.z; acc[3] += br[r] * av.w;
            }
        }
        float4 wv = *(const float4*)(w + (size_t)e * Dd + d0);
        ushort4 o;
        o.x = f2bf(wv.x + LORA_SCALE * acc[0]);
        o.y = f2bf(wv.y + LORA_SCALE * acc[1]);
        o.z = f2bf(wv.z + LORA_SCALE * acc[2]);
        o.w = f2bf(wv.w + LORA_SCALE * acc[3]);
        *(ushort4*)(wqkvb + (size_t)e * Dd + d0) = o;
    } else if (blk < 4 * Dd) {
        int i = ((blk - 3 * Dd) * 256 + tid) * 4;
        float4 v = *(const float4*)(wout + i);
        ushort4 o;
        o.x = f2bf(v.x); o.y = f2bf(v.y); o.z = f2bf(v.z); o.w = f2bf(v.w);
        *(ushort4*)(woutb + i) = o;
    } else if (blk < 4 * Dd + 256) {
        int i = (blk - 4 * Dd) * 256 + tid;    // over Ls*32
        int l = i >> 5;
        int f = i & 31;
        float invf = powf(10000.0f, -(float)f * (1.0f / 32.0f));
        float ang = (float)l * invf;
        float s, c;
        sincosf(ang, &s, &c);
        ropec[i] = c;
        ropes[i] = s;
    } else {
        // ---- LayerNorm(x): wave-per-row, no barriers ----
        const int w64 = tid >> 6;
        const int L = tid & 63;
        const int row = (blk - (4 * Dd + 256)) * 4 + w64;
        const float* xr = x + (size_t)row * Dd;
        float4 v4[4];
        float v[16];
#pragma unroll
        for (int c = 0; c < 4; ++c) {
            v4[c] = *(const float4*)(xr + c * 256 + L * 4);
            v[c * 4 + 0] = v4[c].x; v[c * 4 + 1] = v4[c].y;
            v[c * 4 + 2] = v4[c].z; v[c * 4 + 3] = v4[c].w;
        }
        float s = 0.f;
#pragma unroll
        for (int j = 0; j < 16; ++j) s += v[j];
#pragma unroll
        for (int off = 1; off < 64; off <<= 1) s += __shfl_xor(s, off, 64);
        float mean = s * (1.0f / Dd);
        float sq = 0.f;
#pragma unroll
        for (int j = 0; j < 16; ++j) {
            v[j] -= mean;
            sq += v[j] * v[j];
        }
#pragma unroll
        for (int off = 1; off < 64; off <<= 1) sq += __shfl_xor(sq, off, 64);
        float rs = rsqrtf(sq * (1.0f / Dd) + LN_EPS);
        unsigned short* hr = hb + (size_t)row * Dd;
#pragma unroll
        for (int c = 0; c < 4; ++c) {
            int d = c * 256 + L * 4;
            float4 wv = *(const float4*)(lnw + d);
            float4 bv = *(const float4*)(lnb + d);
            ushort4 o;
            o.x = f2bf(v[c * 4 + 0] * rs * wv.x + bv.x);
            o.y = f2bf(v[c * 4 + 1] * rs * wv.y + bv.y);
            o.z = f2bf(v[c * 4 + 2] * rs * wv.z + bv.z);
            o.w = f2bf(v[c * 4 + 3] * rs * wv.w + bv.w);
            *(ushort4*)(hr + d) = o;
        }
    }
}

// ---------------- 2. MFMA GEMM 128x128: C[M,N] = A[M,K] * B[N,K]^T, bf16 out --
__global__ __launch_bounds__(256) void gemm_bt_mfma(const unsigned short* __restrict__ A,
                                                    const unsigned short* __restrict__ B,
                                                    unsigned short* __restrict__ C,
                                                    int M, int N, int K) {
    __shared__ short As[128 * 64];
    __shared__ short Bs[128 * 64];
    const int tid = threadIdx.x;
    const int w = tid >> 6, lane = tid & 63, quad = lane >> 4, l15 = lane & 15;
    const int m0 = blockIdx.y * 128, n0 = blockIdx.x * 128;
    const int wm = (w & 1) * 64, wn = (w >> 1) * 64;
    f32x4 acc[4][4];
#pragma unroll
    for (int i = 0; i < 4; ++i)
#pragma unroll
        for (int j = 0; j < 4; ++j) acc[i][j] = f32x4{0.f, 0.f, 0.f, 0.f};

    for (int k0 = 0; k0 < K; k0 += 64) {
#pragma unroll
        for (int j = 0; j < 4; ++j) {
            int c = tid + j * 256;
            int row = c >> 3;
            int jg = (c & 7) ^ (row & 7);
            async_copy16(A + (size_t)(m0 + row) * K + k0 + jg * 8, As + c * 8);
        }
#pragma unroll
        for (int j = 0; j < 4; ++j) {
            int c = tid + j * 256;
            int row = c >> 3;
            int jg = (c & 7) ^ (row & 7);
            async_copy16(B + (size_t)(n0 + row) * K + k0 + jg * 8, Bs + c * 8);
        }
        __syncthreads();
#pragma unroll
        for (int ks = 0; ks < 2; ++ks) {
            bf16x8 a[4], b[4];
#pragma unroll
            for (int mi = 0; mi < 4; ++mi) {
                int row = wm + mi * 16 + l15;
                int ch = (ks * 4 + quad) ^ (row & 7);
                a[mi] = *(const bf16x8*)&As[row * 64 + ch * 8];
            }
#pragma unroll
            for (int ni = 0; ni < 4; ++ni) {
                int row = wn + ni * 16 + l15;
                int ch = (ks * 4 + quad) ^ (row & 7);
                b[ni] = *(const bf16x8*)&Bs[row * 64 + ch * 8];
            }
#pragma unroll
            for (int mi = 0; mi < 4; ++mi)
#pragma unroll
                for (int ni = 0; ni < 4; ++ni)
                    acc[mi][ni] = __builtin_amdgcn_mfma_f32_16x16x32_bf16(a[mi], b[ni], acc[mi][ni], 0, 0, 0);
        }
        __syncthreads();
    }
#pragma unroll
    for (int mi = 0; mi < 4; ++mi)
#pragma unroll
        for (int ni = 0; ni < 4; ++ni)
#pragma unroll
            for (int r = 0; r < 4; ++r)
                C[(size_t)(m0 + wm + mi * 16 + quad * 4 + r) * N + n0 + wn + ni * 16 + l15] =
                    f2bf(acc[mi][ni][r]);
}

// ---------------- 2b. MFMA GEMM 128x128, fp32 out — out-projection ------------
// (same structure as gemm_bt_mfma; 16 MFMA per 8 ds_reads vs n64's 8 per 6.)
__global__ __launch_bounds__(256) void gemm_bt_mfma_f32(const unsigned short* __restrict__ A,
                                                        const unsigned short* __restrict__ B,
                                                        float* __restrict__ C,
                                                        int M, int N, int K) {
    __shared__ short As[128 * 64];
    __shared__ short Bs[128 * 64];
    const int tid = threadIdx.x;
    const int w = tid >> 6, lane = tid & 63, quad = lane >> 4, l15 = lane & 15;
    const int m0 = blockIdx.y * 128, n0 = blockIdx.x * 128;
    const int wm = (w & 1) * 64, wn = (w >> 1) * 64;
    f32x4 acc[4][4];
#pragma unroll
    for (int i = 0; i < 4; ++i)
#pragma unroll
        for (int j = 0; j < 4; ++j) acc[i][j] = f32x4{0.f, 0.f, 0.f, 0.f};

    for (int k0 = 0; k0 < K; k0 += 64) {
#pragma unroll
        for (int j = 0; j < 4; ++j) {
            int c = tid + j * 256;
            int row = c >> 3;
            int jg = (c & 7) ^ (row & 7);
            async_copy16(A + (size_t)(m0 + row) * K + k0 + jg * 8, As + c * 8);
        }
#pragma unroll
        for (int j = 0; j < 4; ++j) {
            int c = tid + j * 256;
            int row = c >> 3;
            int jg = (c & 7) ^ (row & 7);
            async_copy16(B + (size_t)(n0 + row) * K + k0 + jg * 8, Bs + c * 8);
        }
        __syncthreads();
#pragma unroll
        for (int ks = 0; ks < 2; ++ks) {
            bf16x8 a[4], b[4];
#pragma unroll
            for (int mi = 0; mi < 4; ++mi) {
                int row = wm + mi * 16 + l15;
                int ch = (ks * 4 + quad) ^ (row & 7);
                a[mi] = *(const bf16x8*)&As[row * 64 + ch * 8];
            }
#pragma unroll
            for (int ni = 0; ni < 4; ++ni) {
                int row = wn + ni * 16 + l15;
                int ch = (ks * 4 + quad) ^ (row & 7);
                b[ni] = *(const bf16x8*)&Bs[row * 64 + ch * 8];
            }
#pragma unroll
            for (int mi = 0; mi < 4; ++mi)
#pragma unroll
                for (int ni = 0; ni < 4; ++ni)
                    acc[mi][ni] = __builtin_amdgcn_mfma_f32_16x16x32_bf16(a[mi], b[ni], acc[mi][ni], 0, 0, 0);
        }
        __syncthreads();
    }
#pragma unroll
    for (int mi = 0; mi < 4; ++mi)
#pragma unroll
        for (int ni = 0; ni < 4; ++ni)
#pragma unroll
            for (int r = 0; r < 4; ++r)
                C[(size_t)(m0 + wm + mi * 16 + quad * 4 + r) * N + n0 + wn + ni * 16 + l15] =
                    acc[mi][ni][r];
}

// ---------------- 3. fused Q/K finalize (wave-per-row) + V transpose ----------
__global__ __launch_bounds__(256) void qkv_final_kernel(const unsigned short* __restrict__ qkvb,
                                                        const float* __restrict__ qlnw,
                                                        const float* __restrict__ klnw,
                                                        const float* __restrict__ ropec,
                                                        const float* __restrict__ ropes,
                                                        unsigned short* __restrict__ qt,
                                                        unsigned short* __restrict__ kt,
                                                        unsigned short* __restrict__ vtt,
                                                        int* __restrict__ wq) {
    const int blk = blockIdx.x;
    const int tid = threadIdx.x;
    if (blk == 0 && tid == 0) *wq = 512;   // init attn work-queue: items 512..1023 stealable
    if (blk < BL / 4) {
        const int w64 = tid >> 6;
        const int L = tid & 63;
        const int row = blk * 4 + w64;
        const int b = row >> 11;
        const int l = row & (Ls - 1);
        const unsigned short* qp = qkvb + (size_t)row * (3 * Dd);
        const unsigned short* kp = qp + Dd;

        bf16x8 qA = *(const bf16x8*)(qp + L * 8);
        bf16x8 qB = *(const bf16x8*)(qp + 512 + L * 8);
        bf16x8 kA = *(const bf16x8*)(kp + L * 8);
        bf16x8 kB = *(const bf16x8*)(kp + 512 + L * 8);
        float vq[16], vk[16];
#pragma unroll
        for (int j = 0; j < 8; ++j) {
            vq[j] = bf2f((unsigned short)qA[j]);
            vq[8 + j] = bf2f((unsigned short)qB[j]);
            vk[j] = bf2f((unsigned short)kA[j]);
            vk[8 + j] = bf2f((unsigned short)kB[j]);
        }
        float sq = 0.f, sk = 0.f;
#pragma unroll
        for (int j = 0; j < 16; ++j) { sq += vq[j]; sk += vk[j]; }
#pragma unroll
        for (int off = 1; off < 64; off <<= 1) {
            sq += __shfl_xor(sq, off, 64);
            sk += __shfl_xor(sk, off, 64);
        }
        float mq = sq * (1.0f / Dd), mk = sk * (1.0f / Dd);
        float vvq = 0.f, vvk = 0.f;
#pragma unroll
        for (int j = 0; j < 16; ++j) {
            vq[j] -= mq; vvq += vq[j] * vq[j];
            vk[j] -= mk; vvk += vk[j] * vk[j];
        }
#pragma unroll
        for (int off = 1; off < 64; off <<= 1) {
            vvq += __shfl_xor(vvq, off, 64);
            vvk += __shfl_xor(vvk, off, 64);
        }
        float rsq = rsqrtf(vvq * (1.0f / Dd) + LN_EPS);
        float rsk = rsqrtf(vvk * (1.0f / Dd) + LN_EPS);

        float yq[16], yk[16];
        {
            float4 w0 = *(const float4*)(qlnw + L * 8);
            float4 w1 = *(const float4*)(qlnw + L * 8 + 4);
            float4 w2 = *(const float4*)(qlnw + 512 + L * 8);
            float4 w3 = *(const float4*)(qlnw + 512 + L * 8 + 4);
            yq[0] = vq[0] * rsq * w0.x; yq[1] = vq[1] * rsq * w0.y;
            yq[2] = vq[2] * rsq * w0.z; yq[3] = vq[3] * rsq * w0.w;
            yq[4] = vq[4] * rsq * w1.x; yq[5] = vq[5] * rsq * w1.y;
            yq[6] = vq[6] * rsq * w1.z; yq[7] = vq[7] * rsq * w1.w;
            yq[8] = vq[8] * rsq * w2.x; yq[9] = vq[9] * rsq * w2.y;
            yq[10] = vq[10] * rsq * w2.z; yq[11] = vq[11] * rsq * w2.w;
            yq[12] = vq[12] * rsq * w3.x; yq[13] = vq[13] * rsq * w3.y;
            yq[14] = vq[14] * rsq * w3.z; yq[15] = vq[15] * rsq * w3.w;
        }
        {
            float4 w0 = *(const float4*)(klnw + L * 8);
            float4 w1 = *(const float4*)(klnw + L * 8 + 4);
            float4 w2 = *(const float4*)(klnw + 512 + L * 8);
            float4 w3 = *(const float4*)(klnw + 512 + L * 8 + 4);
            yk[0] = vk[0] * rsk * w0.x; yk[1] = vk[1] * rsk * w0.y;
            yk[2] = vk[2] * rsk * w0.z; yk[3] = vk[3] * rsk * w0.w;
            yk[4] = vk[4] * rsk * w1.x; yk[5] = vk[5] * rsk * w1.y;
            yk[6] = vk[6] * rsk * w1.z; yk[7] = vk[7] * rsk * w1.w;
            yk[8] = vk[8] * rsk * w2.x; yk[9] = vk[9] * rsk * w2.y;
            yk[10] = vk[10] * rsk * w2.z; yk[11] = vk[11] * rsk * w2.w;
            yk[12] = vk[12] * rsk * w3.x; yk[13] = vk[13] * rsk * w3.y;
            yk[14] = vk[14] * rsk * w3.z; yk[15] = vk[15] * rsk * w3.w;
        }

        float cs[8], sn[8];
        {
            int fbase = l * 32 + (L & 3) * 8;
            float4 c0 = *(const float4*)(ropec + fbase);
            float4 c1 = *(const float4*)(ropec + fbase + 4);
            float4 s0 = *(const float4*)(ropes + fbase);
            float4 s1 = *(const float4*)(ropes + fbase + 4);
            cs[0] = c0.x; cs[1] = c0.y; cs[2] = c0.z; cs[3] = c0.w;
            cs[4] = c1.x; cs[5] = c1.y; cs[6] = c1.z; cs[7] = c1.w;
            sn[0] = s0.x; sn[1] = s0.y; sn[2] = s0.z; sn[3] = s0.w;
            sn[4] = s1.x; sn[5] = s1.y; sn[6] = s1.z; sn[7] = s1.w;
        }
        const float sgn = (L & 4) ? 1.0f : -1.0f;  // dh>=32 ? + : -
        unsigned short outqA[8], outqB[8], outkA[8], outkB[8];
#pragma unroll
        for (int j = 0; j < 8; ++j) {
            float pA = __shfl_xor(yq[j], 4, 64);
            float pB = __shfl_xor(yq[8 + j], 4, 64);
            outqA[j] = f2bf((yq[j] * cs[j] + sgn * pA * sn[j]) * QSCL);
            outqB[j] = f2bf((yq[8 + j] * cs[j] + sgn * pB * sn[j]) * QSCL);
            float pkA = __shfl_xor(yk[j], 4, 64);
            float pkB = __shfl_xor(yk[8 + j], 4, 64);
            outkA[j] = f2bf(yk[j] * cs[j] + sgn * pkA * sn[j]);
            outkB[j] = f2bf(yk[8 + j] * cs[j] + sgn * pkB * sn[j]);
        }
        const int hA = L >> 3;
        const int dh0 = (L & 7) * 8;
        size_t offA = (((size_t)(b * Hh + hA)) * Ls + l) * DHh + dh0;
        size_t offB = (((size_t)(b * Hh + 8 + hA)) * Ls + l) * DHh + dh0;
        *(uint4*)(qt + offA) = *(uint4*)outqA;
        *(uint4*)(qt + offB) = *(uint4*)outqB;
        *(uint4*)(kt + offA) = *(uint4*)outkA;
        *(uint4*)(kt + offB) = *(uint4*)outkB;
    } else {
        // ---- V transpose tile ----
        const int t2 = blk - BL / 4;           // 0..1023
        const int l0 = (t2 & 31) * 64;
        const int h = (t2 >> 5) & 15;
        const int b = t2 >> 9;
        __shared__ short t[64][72];
        const unsigned short* src = qkvb + (size_t)b * Ls * (3 * Dd) + 2 * Dd + h * 64;
#pragma unroll
        for (int j = 0; j < 2; ++j) {
            int g = tid + j * 256;
            int row = g >> 3;
            int c0 = (g & 7) * 8;
            uint4 vv = *(const uint4*)(src + (size_t)(l0 + row) * (3 * Dd) + c0);
            *(uint4*)&t[row][c0] = vv;
        }
        __syncthreads();
        unsigned short* dst = vtt + ((size_t)(b * Hh + h) * DHh) * Ls;
#pragma unroll
        for (int j = 0; j < 2; ++j) {
            int g = tid + j * 256;
            int dh = g >> 3;
            int lc = (g & 7) * 8;
            ushort4 o0, o1;
            unsigned short* p0 = (unsigned short*)&o0;
            unsigned short* p1 = (unsigned short*)&o1;
#pragma unroll
            for (int i = 0; i < 4; ++i) p0[i] = (unsigned short)t[lc + i][dh];
#pragma unroll
            for (int i = 0; i < 4; ++i) p1[i] = (unsigned short)t[lc + 4 + i][dh];
            *(ushort4*)(dst + (size_t)dh * Ls + l0 + lc) = o0;
            *(ushort4*)(dst + (size_t)dh * Ls + l0 + lc + 4) = o1;
        }
    }
}

// ---------------- 5. MFMA flash attention — r2 body + dynamic work queue -----
// Per-item body is the round-2-proven kernel (Q=64, 4 waves, dbuf stage-ahead,
// one barrier/tile, 42.5 us measured). Work items = 1024 (32 (b,h) x 32
// Q-tiles); 512 persistent blocks take item=blockIdx first, then steal via
// device-scope atomicAdd (counter pre-set to 512 by qkv_final). Erases the
// static-assignment tail that held time-avg occupancy at 13-16%.
constexpr int PSP = 76;  // Ps pitch (bank-conflict-free, measured 0 conflicts)

__global__ __launch_bounds__(256) void attn_kernel(const unsigned short* __restrict__ qt,
                                                   const unsigned short* __restrict__ kt,
                                                   const unsigned short* __restrict__ vtt,
                                                   const int* __restrict__ seq_id,
                                                   unsigned short* __restrict__ ctxb,
                                                   int* __restrict__ wq) {
    __shared__ short Ks[2][64 * 64];
    __shared__ short Vs[2][64 * 64];
    __shared__ short Ps[4][16 * PSP];
    __shared__ int sq_s[64];
    __shared__ int item_s;

    const int tid = threadIdx.x;
    const int w = tid >> 6;
    const int lane = tid & 63;
    const int quad = lane >> 4;
    const int l15 = lane & 15;

    int it = blockIdx.x;                   // first item static
    while (it < 1024) {
        const int v = it >> 5;             // b*16 + h  (consecutive items share (b,h))
        const int x = it & 31;
        const int b = v >> 4;
        const int h = v & 15;
        const int q0 = x * 64;

        const size_t base = ((size_t)(b * Hh + h)) * Ls * DHh;
        const size_t base_v = ((size_t)(b * Hh + h)) * DHh * Ls;
        const int* sid = seq_id + (size_t)b * Ls;

        if (tid < 64) sq_s[tid] = sid[q0 + tid];
        const int qmin = sid[q0];
        const int qmax = sid[q0 + 63];

        // prune K-tiles outside this Q-tile's segment range (sid sorted)
        bool need = false;
        if (lane < 32) {
            int kmn = sid[lane * 64];
            int kmx = sid[lane * 64 + 63];
            need = (kmn <= qmax) && (kmx >= qmin);
        }
        unsigned long long bmask = __ballot(need);
        const int t0 = __builtin_ctzll(bmask);
        const int t1 = 64 - __builtin_clzll(bmask);

        // stage K/V tile t into buffer buf (swizzled source -> linear LDS dest)
        auto stage = [&](int buf, int t) {
#pragma unroll
            for (int j = 0; j < 2; ++j) {
                int cc = tid + j * 256;
                int row = cc >> 3;
                int jg = (cc & 7) ^ (row & 7);
                async_copy16(kt + base + (size_t)(t * 64 + row) * DHh + jg * 8,
                             &Ks[buf][cc * 8]);
                async_copy16(vtt + base_v + (size_t)row * Ls + t * 64 + jg * 8,
                             &Vs[buf][cc * 8]);
            }
        };

        stage(0, t0);
        const int qrow = q0 + w * 16 + l15;
        const bf16x8 a0 = *(const bf16x8*)(qt + base + (size_t)qrow * DHh + quad * 8);
        const bf16x8 a1 = *(const bf16x8*)(qt + base + (size_t)qrow * DHh + 32 + quad * 8);

        int sqv[4];
        float lsum[4] = {0.f, 0.f, 0.f, 0.f};
        f32x4 O[4];
#pragma unroll
        for (int r = 0; r < 4; ++r) O[r] = f32x4{0.f, 0.f, 0.f, 0.f};

        __syncthreads();   // drains stage(t0) + publishes sq_s
#pragma unroll
        for (int r = 0; r < 4; ++r) sqv[r] = sq_s[w * 16 + quad * 4 + r];

        for (int t = t0; t < t1; ++t) {
            const int cur = (t - t0) & 1;
            if (t + 1 < t1) stage(cur ^ 1, t + 1);   // prefetch next tile, no wait
            const int k0 = t * 64;

            f32x4 s[4];
#pragma unroll
            for (int kg = 0; kg < 4; ++kg) {
                int krow = kg * 16 + l15;
                bf16x8 b0 = *(const bf16x8*)&Ks[cur][krow * 64 + ((0 + quad) ^ (krow & 7)) * 8];
                bf16x8 b1 = *(const bf16x8*)&Ks[cur][krow * 64 + ((4 + quad) ^ (krow & 7)) * 8];
                f32x4 acc = {0.f, 0.f, 0.f, 0.f};
                acc = __builtin_amdgcn_mfma_f32_16x16x32_bf16(a0, b0, acc, 0, 0, 0);
                acc = __builtin_amdgcn_mfma_f32_16x16x32_bf16(a1, b1, acc, 0, 0, 0);
                s[kg] = acc;
            }

            const int kmn = sid[k0];
            const int kmx = sid[k0 + 63];
            const bool nomask = (kmn == kmx) && (qmin == qmax) && (kmn == qmin);
            if (!nomask) {
#pragma unroll
                for (int kg = 0; kg < 4; ++kg) {
                    int skv = sid[k0 + kg * 16 + l15];
#pragma unroll
                    for (int r = 0; r < 4; ++r)
                        if (sqv[r] != skv) s[kg][r] = -3.0e38f;
                }
            }
#pragma unroll
            for (int kg = 0; kg < 4; ++kg)
#pragma unroll
                for (int r = 0; r < 4; ++r)
                    s[kg][r] = __builtin_amdgcn_exp2f(s[kg][r]);
#pragma unroll
            for (int r = 0; r < 4; ++r)
                lsum[r] += s[0][r] + s[1][r] + s[2][r] + s[3][r];

            // P -> per-wave LDS (layout transform for PV A-fragment); no barrier:
            // DS pipe is in-order within a wave, compiler inserts lgkmcnt waits.
#pragma unroll
            for (int kg = 0; kg < 4; ++kg)
#pragma unroll
                for (int r = 0; r < 4; ++r)
                    Ps[w][(quad * 4 + r) * PSP + kg * 16 + l15] = (short)f2bf(s[kg][r]);

            bf16x8 pa0 = *(const bf16x8*)&Ps[w][l15 * PSP + quad * 8];
            bf16x8 pa1 = *(const bf16x8*)&Ps[w][l15 * PSP + 32 + quad * 8];
#pragma unroll
            for (int ng = 0; ng < 4; ++ng) {
                int vrow = ng * 16 + l15;
                bf16x8 vb0 = *(const bf16x8*)&Vs[cur][vrow * 64 + ((0 + quad) ^ (vrow & 7)) * 8];
                bf16x8 vb1 = *(const bf16x8*)&Vs[cur][vrow * 64 + ((4 + quad) ^ (vrow & 7)) * 8];
                O[ng] = __builtin_amdgcn_mfma_f32_16x16x32_bf16(pa0, vb0, O[ng], 0, 0, 0);
                O[ng] = __builtin_amdgcn_mfma_f32_16x16x32_bf16(pa1, vb1, O[ng], 0, 0, 0);
            }

            // single barrier per K-tile: all waves done reading buf[cur] AND the
            // prefetch DMA into buf[cur^1] drained (aged through compute).
            __syncthreads();
        }

        // row-sum reduce over the 16 l15 lanes (quad fixed = row identity)
#pragma unroll
        for (int off = 1; off < 16; off <<= 1)
#pragma unroll
            for (int r = 0; r < 4; ++r)
                lsum[r] += __shfl_xor(lsum[r], off, 64);
        float inv_l[4];
#pragma unroll
        for (int r = 0; r < 4; ++r) inv_l[r] = 1.0f / lsum[r];
#pragma unroll
        for (int ng = 0; ng < 4; ++ng)
#pragma unroll
            for (int r = 0; r < 4; ++r) {
                int q = q0 + w * 16 + quad * 4 + r;
                ctxb[((size_t)b * Ls + q) * Dd + h * DHh + ng * 16 + l15] =
                    f2bf(O[ng][r] * inv_l[r]);
            }

        // fetch next work item (device-scope atomic; block-uniform broadcast)
        if (tid == 0) item_s = atomicAdd(wq, 1);
        __syncthreads();
        it = item_s;
    }
}

// ---------------- launcher ----------------
extern "C" void kernel_launch(void* const* d_in, const int* in_sizes, int n_in,
                              void* d_out, int out_size, void* d_ws, size_t ws_size,
                              hipStream_t stream) {
    const float* x = (const float*)d_in[0];
    const int* seq_id = (const int*)d_in[1];
    const float* ln_w = (const float*)d_in[2];
    const float* ln_b = (const float*)d_in[3];
    const float* w_qkv = (const float*)d_in[4];
    const float* q_lora_a = (const float*)d_in[5];
    const float* q_lora_b = (const float*)d_in[6];
    const float* v_lora_a = (const float*)d_in[7];
    const float* v_lora_b = (const float*)d_in[8];
    const float* q_ln_w = (const float*)d_in[9];
    const float* k_ln_w = (const float*)d_in[10];
    const float* w_out = (const float*)d_in[11];
    float* out = (float*)d_out;

    const size_t SZ = (size_t)BL * Dd;        // 4M elements
    float* p = (float*)d_ws;
    float* ropec = p;          p += (size_t)Ls * 32;
    float* ropes = p;          p += (size_t)Ls * 32;
    unsigned short* ub = (unsigned short*)p;
    unsigned short* qkvb = ub; ub += 3 * SZ;  // bf16 [BL, 3D]
    unsigned short* hb = ub;   ub += SZ;      // bf16 [BL, D]
    unsigned short* qt = ub;   ub += SZ;      // bf16 [B,H,L,DH] (prescaled)
    unsigned short* kt = ub;   ub += SZ;
    unsigned short* vtt = ub;  ub += SZ;      // bf16 [B,H,DH,L]
    unsigned short* ctxb = ub; ub += SZ;      // bf16 [BL, D]
    unsigned short* wqkvb = ub; ub += (size_t)3 * Dd * Dd;
    unsigned short* woutb = ub; ub += (size_t)Dd * Dd;
    int* wq = (int*)ub;        ub += 64;      // attn work-queue counter

    prep_ln_kernel<<<4 * Dd + 256 + BL / 4, 256, 0, stream>>>(
        w_qkv, q_lora_a, q_lora_b, v_lora_a, v_lora_b, w_out,
        x, ln_w, ln_b, wqkvb, woutb, ropec, ropes, hb);
    {
        dim3 g(3 * Dd / 128, BL / 128);
        gemm_bt_mfma<<<g, 256, 0, stream>>>(hb, wqkvb, qkvb, BL, 3 * Dd, Dd);
    }
    qkv_final_kernel<<<BL / 4 + 1024, 256, 0, stream>>>(qkvb, q_ln_w, k_ln_w,
                                                        ropec, ropes, qt, kt, vtt, wq);
    attn_kernel<<<512, 256, 0, stream>>>(qt, kt, vtt, seq_id, ctxb, wq);
    {
        dim3 g(Dd / 128, BL / 128);
        gemm_bt_mfma_f32<<<g, 256, 0, stream>>>(ctxb, woutb, out, BL, Dd, Dd);
    }
}

// Round 8
// 201.545 us; speedup vs baseline: 1.1042x; 1.1042x over previous
//
#include <hip/hip_runtime.h>
#include <hip/hip_bf16.h>
#include <cmath>

// Problem constants (fixed by reference)
constexpr int Bb = 2;
constexpr int Ls = 2048;
constexpr int Dd = 1024;
constexpr int Hh = 16;
constexpr int DHh = 64;
constexpr int Rr = 32;
constexpr int BL = Bb * Ls;          // 4096
constexpr float LORA_SCALE = 2.0f;   // 64/32
constexpr float LN_EPS = 1e-5f;
constexpr float ATTN_SCALE = 0.125f; // 1/sqrt(64)
constexpr float LOG2E = 1.4426950408889634f;
constexpr float QSCL = ATTN_SCALE * LOG2E;  // folded into qt

typedef __attribute__((ext_vector_type(8))) short bf16x8;
typedef __attribute__((ext_vector_type(4))) float f32x4;

__device__ __forceinline__ unsigned short f2bf(float f) {
    __hip_bfloat16 b = __float2bfloat16(f);
    return *reinterpret_cast<unsigned short*>(&b);
}
__device__ __forceinline__ float bf2f(unsigned short u) {
    unsigned int x = ((unsigned int)u) << 16;
    return __uint_as_float(x);
}
__device__ __forceinline__ void async_copy16(const void* g, void* l) {
    __builtin_amdgcn_global_load_lds(
        (__attribute__((address_space(1))) void*)(void*)(size_t)g,
        (__attribute__((address_space(3))) void*)l, 16, 0, 0);
}

// ---------------- 0. fused prep: merge-wqkv | cast w_out | rope | ln_x --------
__global__ __launch_bounds__(256) void prep_ln_kernel(const float* __restrict__ w,
                                                      const float* __restrict__ qa,
                                                      const float* __restrict__ qb,
                                                      const float* __restrict__ va,
                                                      const float* __restrict__ vb,
                                                      const float* __restrict__ wout,
                                                      const float* __restrict__ x,
                                                      const float* __restrict__ lnw,
                                                      const float* __restrict__ lnb,
                                                      unsigned short* __restrict__ wqkvb,
                                                      unsigned short* __restrict__ woutb,
                                                      float* __restrict__ ropec,
                                                      float* __restrict__ ropes,
                                                      unsigned short* __restrict__ hb) {
    const int blk = blockIdx.x;
    const int tid = threadIdx.x;
    if (blk < 3 * Dd) {
        const int e = blk;
        const int d0 = tid * 4;
        __shared__ float br[Rr];
        const bool isq = (e < Dd);
        const bool isv = (e >= 2 * Dd);
        const float* bsrc = isq ? (qb + (size_t)e * Rr)
                                : (isv ? (vb + (size_t)(e - 2 * Dd) * Rr) : nullptr);
        const float* asrc = isq ? qa : va;
        if (bsrc && tid < Rr) br[tid] = bsrc[tid];
        __syncthreads();
        float acc[4] = {0.f, 0.f, 0.f, 0.f};
        if (bsrc) {
#pragma unroll 8
            for (int r = 0; r < Rr; ++r) {
                float4 av = *(const float4*)(asrc + (size_t)r * Dd + d0);
                acc[0] += br[r] * av.x; acc[1] += br[r] * av.y;
                acc[2] += br[r] * av.z; acc[3] += br[r] * av.w;
            }
        }
        float4 wv = *(const float4*)(w + (size_t)e * Dd + d0);
        ushort4 o;
        o.x = f2bf(wv.x + LORA_SCALE * acc[0]);
        o.y = f2bf(wv.y + LORA_SCALE * acc[1]);
        o.z = f2bf(wv.z + LORA_SCALE * acc[2]);
        o.w = f2bf(wv.w + LORA_SCALE * acc[3]);
        *(ushort4*)(wqkvb + (size_t)e * Dd + d0) = o;
    } else if (blk < 4 * Dd) {
        int i = ((blk - 3 * Dd) * 256 + tid) * 4;
        float4 v = *(const float4*)(wout + i);
        ushort4 o;
        o.x = f2bf(v.x); o.y = f2bf(v.y); o.z = f2bf(v.z); o.w = f2bf(v.w);
        *(ushort4*)(woutb + i) = o;
    } else if (blk < 4 * Dd + 256) {
        int i = (blk - 4 * Dd) * 256 + tid;    // over Ls*32
        int l = i >> 5;
        int f = i & 31;
        float invf = powf(10000.0f, -(float)f * (1.0f / 32.0f));
        float ang = (float)l * invf;
        float s, c;
        sincosf(ang, &s, &c);
        ropec[i] = c;
        ropes[i] = s;
    } else {
        // ---- LayerNorm(x): wave-per-row, no barriers ----
        const int w64 = tid >> 6;
        const int L = tid & 63;
        const int row = (blk - (4 * Dd + 256)) * 4 + w64;
        const float* xr = x + (size_t)row * Dd;
        float4 v4[4];
        float v[16];
#pragma unroll
        for (int c = 0; c < 4; ++c) {
            v4[c] = *(const float4*)(xr + c * 256 + L * 4);
            v[c * 4 + 0] = v4[c].x; v[c * 4 + 1] = v4[c].y;
            v[c * 4 + 2] = v4[c].z; v[c * 4 + 3] = v4[c].w;
        }
        float s = 0.f;
#pragma unroll
        for (int j = 0; j < 16; ++j) s += v[j];
#pragma unroll
        for (int off = 1; off < 64; off <<= 1) s += __shfl_xor(s, off, 64);
        float mean = s * (1.0f / Dd);
        float sq = 0.f;
#pragma unroll
        for (int j = 0; j < 16; ++j) {
            v[j] -= mean;
            sq += v[j] * v[j];
        }
#pragma unroll
        for (int off = 1; off < 64; off <<= 1) sq += __shfl_xor(sq, off, 64);
        float rs = rsqrtf(sq * (1.0f / Dd) + LN_EPS);
        unsigned short* hr = hb + (size_t)row * Dd;
#pragma unroll
        for (int c = 0; c < 4; ++c) {
            int d = c * 256 + L * 4;
            float4 wv = *(const float4*)(lnw + d);
            float4 bv = *(const float4*)(lnb + d);
            ushort4 o;
            o.x = f2bf(v[c * 4 + 0] * rs * wv.x + bv.x);
            o.y = f2bf(v[c * 4 + 1] * rs * wv.y + bv.y);
            o.z = f2bf(v[c * 4 + 2] * rs * wv.z + bv.z);
            o.w = f2bf(v[c * 4 + 3] * rs * wv.w + bv.w);
            *(ushort4*)(hr + d) = o;
        }
    }
}

// ---------------- 2. MFMA GEMM 256x256, 8-wave, 4-phase interleave (QKV) -----
// §5 8-phase template (safe tile-granular variant): per K-tile (BK=64), 4
// phases of {ds_read frag subtile | stage-issue -> raw s_barrier ->
// lgkmcnt(0) -> setprio(1) 16 MFMA setprio(0) -> raw s_barrier}. stage(t+1)
// goes into dbuf[cur^1] during P1/P2 (loads age >=2 phases), ONE vmcnt(0)
// per K-tile at P4 (vs the old kernel's two full drains per K-step).
// Race-free: writes never target the buffer being read; tile boundary has
// drain + 2 barriers. Grid 12x16=192 blocks, 1 block/CU, LDS 128 KiB.
constexpr int GTILES = 16;   // K=1024 / BK=64

__global__ __launch_bounds__(512, 2) void gemm_qkv_256(const unsigned short* __restrict__ A,
                                                       const unsigned short* __restrict__ B,
                                                       unsigned short* __restrict__ C,
                                                       int M, int N, int K) {
    __shared__ short As[2][256 * 64];
    __shared__ short Bs[2][256 * 64];
    const int tid = threadIdx.x;
    const int w = tid >> 6;          // 0..7
    const int lane = tid & 63;
    const int quad = lane >> 4, l15 = lane & 15;
    const int wr = w >> 2;           // 0..1  (M half: 128 rows)
    const int wc = w & 3;            // 0..3  (N quarter: 64 cols)
    const int m0 = blockIdx.y * 256, n0 = blockIdx.x * 256;

    f32x4 acc[8][4];
#pragma unroll
    for (int i = 0; i < 8; ++i)
#pragma unroll
        for (int j = 0; j < 4; ++j) acc[i][j] = f32x4{0.f, 0.f, 0.f, 0.f};

    // stage one K-tile (256 rows x 64 cols bf16 = 32KB) of A or B: 4 instr/thr
    auto stageA = [&](int buf, int kt) {
#pragma unroll
        for (int i = 0; i < 4; ++i) {
            int c = tid + i * 512;            // 0..2047
            int row = c >> 3;                 // 0..255
            int jg = (c & 7) ^ (row & 7);
            async_copy16(A + (size_t)(m0 + row) * K + kt * 64 + jg * 8,
                         &As[buf][c * 8]);
        }
    };
    auto stageB = [&](int buf, int kt) {
#pragma unroll
        for (int i = 0; i < 4; ++i) {
            int c = tid + i * 512;
            int row = c >> 3;
            int jg = (c & 7) ^ (row & 7);
            async_copy16(B + (size_t)(n0 + row) * K + kt * 64 + jg * 8,
                         &Bs[buf][c * 8]);
        }
    };

    stageA(0, 0);
    stageB(0, 0);
    asm volatile("s_waitcnt vmcnt(0)");
    asm volatile("" ::: "memory");
    __builtin_amdgcn_s_barrier();

    for (int t = 0; t < GTILES; ++t) {
        const int cur = t & 1;
        const short* as = As[cur];
        const short* bs = Bs[cur];
        bf16x8 af[8], bfr[2];

        // ---- P1: A frags ks=0 (8 dsr) + B ni=0,1 ks=0 (2 dsr) | stage A(t+1)
#pragma unroll
        for (int mi = 0; mi < 8; ++mi) {
            int row = wr * 128 + mi * 16 + l15;
            af[mi] = *(const bf16x8*)&as[row * 64 + ((0 + quad) ^ (row & 7)) * 8];
        }
#pragma unroll
        for (int ni = 0; ni < 2; ++ni) {
            int row = wc * 64 + ni * 16 + l15;
            bfr[ni] = *(const bf16x8*)&bs[row * 64 + ((0 + quad) ^ (row & 7)) * 8];
        }
        if (t + 1 < GTILES) stageA(cur ^ 1, t + 1);
        asm volatile("" ::: "memory");
        __builtin_amdgcn_s_barrier();
        asm volatile("s_waitcnt lgkmcnt(0)");
        __builtin_amdgcn_s_setprio(1);
#pragma unroll
        for (int mi = 0; mi < 8; ++mi)
#pragma unroll
            for (int ni = 0; ni < 2; ++ni)
                acc[mi][ni] = __builtin_amdgcn_mfma_f32_16x16x32_bf16(af[mi], bfr[ni], acc[mi][ni], 0, 0, 0);
        __builtin_amdgcn_s_setprio(0);
        asm volatile("" ::: "memory");
        __builtin_amdgcn_s_barrier();

        // ---- P2: B ni=2,3 ks=0 (2 dsr) | stage B(t+1)
#pragma unroll
        for (int ni = 0; ni < 2; ++ni) {
            int row = wc * 64 + (2 + ni) * 16 + l15;
            bfr[ni] = *(const bf16x8*)&bs[row * 64 + ((0 + quad) ^ (row & 7)) * 8];
        }
        if (t + 1 < GTILES) stageB(cur ^ 1, t + 1);
        asm volatile("" ::: "memory");
        __builtin_amdgcn_s_barrier();
        asm volatile("s_waitcnt lgkmcnt(0)");
        __builtin_amdgcn_s_setprio(1);
#pragma unroll
        for (int mi = 0; mi < 8; ++mi)
#pragma unroll
            for (int ni = 0; ni < 2; ++ni)
                acc[mi][2 + ni] = __builtin_amdgcn_mfma_f32_16x16x32_bf16(af[mi], bfr[ni], acc[mi][2 + ni], 0, 0, 0);
        __builtin_amdgcn_s_setprio(0);
        asm volatile("" ::: "memory");
        __builtin_amdgcn_s_barrier();

        // ---- P3: A frags ks=1 (8 dsr) + B ni=0,1 ks=1 (2 dsr)
#pragma unroll
        for (int mi = 0; mi < 8; ++mi) {
            int row = wr * 128 + mi * 16 + l15;
            af[mi] = *(const bf16x8*)&as[row * 64 + ((4 + quad) ^ (row & 7)) * 8];
        }
#pragma unroll
        for (int ni = 0; ni < 2; ++ni) {
            int row = wc * 64 + ni * 16 + l15;
            bfr[ni] = *(const bf16x8*)&bs[row * 64 + ((4 + quad) ^ (row & 7)) * 8];
        }
        asm volatile("" ::: "memory");
        __builtin_amdgcn_s_barrier();
        asm volatile("s_waitcnt lgkmcnt(0)");
        __builtin_amdgcn_s_setprio(1);
#pragma unroll
        for (int mi = 0; mi < 8; ++mi)
#pragma unroll
            for (int ni = 0; ni < 2; ++ni)
                acc[mi][ni] = __builtin_amdgcn_mfma_f32_16x16x32_bf16(af[mi], bfr[ni], acc[mi][ni], 0, 0, 0);
        __builtin_amdgcn_s_setprio(0);
        asm volatile("" ::: "memory");
        __builtin_amdgcn_s_barrier();

        // ---- P4: B ni=2,3 ks=1 (2 dsr) | vmcnt(0) drains stage(t+1)
#pragma unroll
        for (int ni = 0; ni < 2; ++ni) {
            int row = wc * 64 + (2 + ni) * 16 + l15;
            bfr[ni] = *(const bf16x8*)&bs[row * 64 + ((4 + quad) ^ (row & 7)) * 8];
        }
        asm volatile("s_waitcnt vmcnt(0)");
        asm volatile("" ::: "memory");
        __builtin_amdgcn_s_barrier();
        asm volatile("s_waitcnt lgkmcnt(0)");
        __builtin_amdgcn_s_setprio(1);
#pragma unroll
        for (int mi = 0; mi < 8; ++mi)
#pragma unroll
            for (int ni = 0; ni < 2; ++ni)
                acc[mi][2 + ni] = __builtin_amdgcn_mfma_f32_16x16x32_bf16(af[mi], bfr[ni], acc[mi][2 + ni], 0, 0, 0);
        __builtin_amdgcn_s_setprio(0);
        asm volatile("" ::: "memory");
        __builtin_amdgcn_s_barrier();
    }

#pragma unroll
    for (int mi = 0; mi < 8; ++mi)
#pragma unroll
        for (int ni = 0; ni < 4; ++ni)
#pragma unroll
            for (int r = 0; r < 4; ++r)
                C[(size_t)(m0 + wr * 128 + mi * 16 + quad * 4 + r) * N +
                  n0 + wc * 64 + ni * 16 + l15] = f2bf(acc[mi][ni][r]);
}

// ---------------- 2b. MFMA GEMM 128x64 tile (fp32 out) — out-projection -------
__global__ __launch_bounds__(256) void gemm_bt_mfma_n64(const unsigned short* __restrict__ A,
                                                        const unsigned short* __restrict__ B,
                                                        float* __restrict__ C,
                                                        int M, int N, int K) {
    __shared__ short As[128 * 64];
    __shared__ short Bs[64 * 64];
    const int tid = threadIdx.x;
    const int w = tid >> 6, lane = tid & 63, quad = lane >> 4, l15 = lane & 15;
    const int m0 = blockIdx.y * 128, n0 = blockIdx.x * 64;
    const int wm = (w & 1) * 64, wn = (w >> 1) * 32;
    f32x4 acc[4][2];
#pragma unroll
    for (int i = 0; i < 4; ++i)
#pragma unroll
        for (int j = 0; j < 2; ++j) acc[i][j] = f32x4{0.f, 0.f, 0.f, 0.f};

    for (int k0 = 0; k0 < K; k0 += 64) {
#pragma unroll
        for (int j = 0; j < 4; ++j) {
            int c = tid + j * 256;
            int row = c >> 3;
            int jg = (c & 7) ^ (row & 7);
            async_copy16(A + (size_t)(m0 + row) * K + k0 + jg * 8, As + c * 8);
        }
#pragma unroll
        for (int j = 0; j < 2; ++j) {
            int c = tid + j * 256;
            int row = c >> 3;
            int jg = (c & 7) ^ (row & 7);
            async_copy16(B + (size_t)(n0 + row) * K + k0 + jg * 8, Bs + c * 8);
        }
        __syncthreads();
#pragma unroll
        for (int ks = 0; ks < 2; ++ks) {
            bf16x8 a[4], b[2];
#pragma unroll
            for (int mi = 0; mi < 4; ++mi) {
                int row = wm + mi * 16 + l15;
                int ch = (ks * 4 + quad) ^ (row & 7);
                a[mi] = *(const bf16x8*)&As[row * 64 + ch * 8];
            }
#pragma unroll
            for (int ni = 0; ni < 2; ++ni) {
                int row = wn + ni * 16 + l15;
                int ch = (ks * 4 + quad) ^ (row & 7);
                b[ni] = *(const bf16x8*)&Bs[row * 64 + ch * 8];
            }
#pragma unroll
            for (int mi = 0; mi < 4; ++mi)
#pragma unroll
                for (int ni = 0; ni < 2; ++ni)
                    acc[mi][ni] = __builtin_amdgcn_mfma_f32_16x16x32_bf16(a[mi], b[ni], acc[mi][ni], 0, 0, 0);
        }
        __syncthreads();
    }
#pragma unroll
    for (int mi = 0; mi < 4; ++mi)
#pragma unroll
        for (int ni = 0; ni < 2; ++ni)
#pragma unroll
            for (int r = 0; r < 4; ++r)
                C[(size_t)(m0 + wm + mi * 16 + quad * 4 + r) * N + n0 + wn + ni * 16 + l15] =
                    acc[mi][ni][r];
}

// ---------------- 3. fused Q/K finalize (wave-per-row) + V transpose ----------
__global__ __launch_bounds__(256) void qkv_final_kernel(const unsigned short* __restrict__ qkvb,
                                                        const float* __restrict__ qlnw,
                                                        const float* __restrict__ klnw,
                                                        const float* __restrict__ ropec,
                                                        const float* __restrict__ ropes,
                                                        unsigned short* __restrict__ qt,
                                                        unsigned short* __restrict__ kt,
                                                        unsigned short* __restrict__ vtt) {
    const int blk = blockIdx.x;
    const int tid = threadIdx.x;
    if (blk < BL / 4) {
        const int w64 = tid >> 6;
        const int L = tid & 63;
        const int row = blk * 4 + w64;
        const int b = row >> 11;
        const int l = row & (Ls - 1);
        const unsigned short* qp = qkvb + (size_t)row * (3 * Dd);
        const unsigned short* kp = qp + Dd;

        bf16x8 qA = *(const bf16x8*)(qp + L * 8);
        bf16x8 qB = *(const bf16x8*)(qp + 512 + L * 8);
        bf16x8 kA = *(const bf16x8*)(kp + L * 8);
        bf16x8 kB = *(const bf16x8*)(kp + 512 + L * 8);
        float vq[16], vk[16];
#pragma unroll
        for (int j = 0; j < 8; ++j) {
            vq[j] = bf2f((unsigned short)qA[j]);
            vq[8 + j] = bf2f((unsigned short)qB[j]);
            vk[j] = bf2f((unsigned short)kA[j]);
            vk[8 + j] = bf2f((unsigned short)kB[j]);
        }
        float sq = 0.f, sk = 0.f;
#pragma unroll
        for (int j = 0; j < 16; ++j) { sq += vq[j]; sk += vk[j]; }
#pragma unroll
        for (int off = 1; off < 64; off <<= 1) {
            sq += __shfl_xor(sq, off, 64);
            sk += __shfl_xor(sk, off, 64);
        }
        float mq = sq * (1.0f / Dd), mk = sk * (1.0f / Dd);
        float vvq = 0.f, vvk = 0.f;
#pragma unroll
        for (int j = 0; j < 16; ++j) {
            vq[j] -= mq; vvq += vq[j] * vq[j];
            vk[j] -= mk; vvk += vk[j] * vk[j];
        }
#pragma unroll
        for (int off = 1; off < 64; off <<= 1) {
            vvq += __shfl_xor(vvq, off, 64);
            vvk += __shfl_xor(vvk, off, 64);
        }
        float rsq = rsqrtf(vvq * (1.0f / Dd) + LN_EPS);
        float rsk = rsqrtf(vvk * (1.0f / Dd) + LN_EPS);

        float yq[16], yk[16];
        {
            float4 w0 = *(const float4*)(qlnw + L * 8);
            float4 w1 = *(const float4*)(qlnw + L * 8 + 4);
            float4 w2 = *(const float4*)(qlnw + 512 + L * 8);
            float4 w3 = *(const float4*)(qlnw + 512 + L * 8 + 4);
            yq[0] = vq[0] * rsq * w0.x; yq[1] = vq[1] * rsq * w0.y;
            yq[2] = vq[2] * rsq * w0.z; yq[3] = vq[3] * rsq * w0.w;
            yq[4] = vq[4] * rsq * w1.x; yq[5] = vq[5] * rsq * w1.y;
            yq[6] = vq[6] * rsq * w1.z; yq[7] = vq[7] * rsq * w1.w;
            yq[8] = vq[8] * rsq * w2.x; yq[9] = vq[9] * rsq * w2.y;
            yq[10] = vq[10] * rsq * w2.z; yq[11] = vq[11] * rsq * w2.w;
            yq[12] = vq[12] * rsq * w3.x; yq[13] = vq[13] * rsq * w3.y;
            yq[14] = vq[14] * rsq * w3.z; yq[15] = vq[15] * rsq * w3.w;
        }
        {
            float4 w0 = *(const float4*)(klnw + L * 8);
            float4 w1 = *(const float4*)(klnw + L * 8 + 4);
            float4 w2 = *(const float4*)(klnw + 512 + L * 8);
            float4 w3 = *(const float4*)(klnw + 512 + L * 8 + 4);
            yk[0] = vk[0] * rsk * w0.x; yk[1] = vk[1] * rsk * w0.y;
            yk[2] = vk[2] * rsk * w0.z; yk[3] = vk[3] * rsk * w0.w;
            yk[4] = vk[4] * rsk * w1.x; yk[5] = vk[5] * rsk * w1.y;
            yk[6] = vk[6] * rsk * w1.z; yk[7] = vk[7] * rsk * w1.w;
            yk[8] = vk[8] * rsk * w2.x; yk[9] = vk[9] * rsk * w2.y;
            yk[10] = vk[10] * rsk * w2.z; yk[11] = vk[11] * rsk * w2.w;
            yk[12] = vk[12] * rsk * w3.x; yk[13] = vk[13] * rsk * w3.y;
            yk[14] = vk[14] * rsk * w3.z; yk[15] = vk[15] * rsk * w3.w;
        }

        float cs[8], sn[8];
        {
            int fbase = l * 32 + (L & 3) * 8;
            float4 c0 = *(const float4*)(ropec + fbase);
            float4 c1 = *(const float4*)(ropec + fbase + 4);
            float4 s0 = *(const float4*)(ropes + fbase);
            float4 s1 = *(const float4*)(ropes + fbase + 4);
            cs[0] = c0.x; cs[1] = c0.y; cs[2] = c0.z; cs[3] = c0.w;
            cs[4] = c1.x; cs[5] = c1.y; cs[6] = c1.z; cs[7] = c1.w;
            sn[0] = s0.x; sn[1] = s0.y; sn[2] = s0.z; sn[3] = s0.w;
            sn[4] = s1.x; sn[5] = s1.y; sn[6] = s1.z; sn[7] = s1.w;
        }
        const float sgn = (L & 4) ? 1.0f : -1.0f;  // dh>=32 ? + : -
        unsigned short outqA[8], outqB[8], outkA[8], outkB[8];
#pragma unroll
        for (int j = 0; j < 8; ++j) {
            float pA = __shfl_xor(yq[j], 4, 64);
            float pB = __shfl_xor(yq[8 + j], 4, 64);
            outqA[j] = f2bf((yq[j] * cs[j] + sgn * pA * sn[j]) * QSCL);
            outqB[j] = f2bf((yq[8 + j] * cs[j] + sgn * pB * sn[j]) * QSCL);
            float pkA = __shfl_xor(yk[j], 4, 64);
            float pkB = __shfl_xor(yk[8 + j], 4, 64);
            outkA[j] = f2bf(yk[j] * cs[j] + sgn * pkA * sn[j]);
            outkB[j] = f2bf(yk[8 + j] * cs[j] + sgn * pkB * sn[j]);
        }
        const int hA = L >> 3;
        const int dh0 = (L & 7) * 8;
        size_t offA = (((size_t)(b * Hh + hA)) * Ls + l) * DHh + dh0;
        size_t offB = (((size_t)(b * Hh + 8 + hA)) * Ls + l) * DHh + dh0;
        *(uint4*)(qt + offA) = *(uint4*)outqA;
        *(uint4*)(qt + offB) = *(uint4*)outqB;
        *(uint4*)(kt + offA) = *(uint4*)outkA;
        *(uint4*)(kt + offB) = *(uint4*)outkB;
    } else {
        // ---- V transpose tile ----
        const int t2 = blk - BL / 4;           // 0..1023
        const int l0 = (t2 & 31) * 64;
        const int h = (t2 >> 5) & 15;
        const int b = t2 >> 9;
        __shared__ short t[64][72];
        const unsigned short* src = qkvb + (size_t)b * Ls * (3 * Dd) + 2 * Dd + h * 64;
#pragma unroll
        for (int j = 0; j < 2; ++j) {
            int g = tid + j * 256;
            int row = g >> 3;
            int c0 = (g & 7) * 8;
            uint4 vv = *(const uint4*)(src + (size_t)(l0 + row) * (3 * Dd) + c0);
            *(uint4*)&t[row][c0] = vv;
        }
        __syncthreads();
        unsigned short* dst = vtt + ((size_t)(b * Hh + h) * DHh) * Ls;
#pragma unroll
        for (int j = 0; j < 2; ++j) {
            int g = tid + j * 256;
            int dh = g >> 3;
            int lc = (g & 7) * 8;
            ushort4 o0, o1;
            unsigned short* p0 = (unsigned short*)&o0;
            unsigned short* p1 = (unsigned short*)&o1;
#pragma unroll
            for (int i = 0; i < 4; ++i) p0[i] = (unsigned short)t[lc + i][dh];
#pragma unroll
            for (int i = 0; i < 4; ++i) p1[i] = (unsigned short)t[lc + 4 + i][dh];
            *(ushort4*)(dst + (size_t)dh * Ls + l0 + lc) = o0;
            *(ushort4*)(dst + (size_t)dh * Ls + l0 + lc + 4) = o1;
        }
    }
}

// ---------------- 5. MFMA flash attention — Q=128, 8 waves, dbuf pipeline ----
// (round-3 configuration: session-best wall 202.9)
constexpr int PSP = 76;  // Ps pitch (bank-conflict-free, measured 0 conflicts)

__global__ __launch_bounds__(512) void attn_kernel(const unsigned short* __restrict__ qt,
                                                   const unsigned short* __restrict__ kt,
                                                   const unsigned short* __restrict__ vtt,
                                                   const int* __restrict__ seq_id,
                                                   unsigned short* __restrict__ ctxb) {
    const int id = blockIdx.x;            // 0..511
    const int c8 = id & 7;                // XCD-swizzle: h%8 pinned per XCD
    const int x = (id >> 3) & 15;
    const int g4 = id >> 7;               // 0..3
    const int v = c8 + 8 * g4;            // h + 16*b
    const int b = v >> 4;
    const int h = v & 15;
    const int q0 = x * 128;

    const size_t base = ((size_t)(b * Hh + h)) * Ls * DHh;
    const size_t base_v = ((size_t)(b * Hh + h)) * DHh * Ls;
    const int* sid = seq_id + (size_t)b * Ls;

    __shared__ short Ks[2][64 * 64];
    __shared__ short Vs[2][64 * 64];
    __shared__ short Ps[8][16 * PSP];
    __shared__ int sq_s[128];

    const int tid = threadIdx.x;
    const int w = tid >> 6;               // 0..7
    const int lane = tid & 63;
    const int quad = lane >> 4;
    const int l15 = lane & 15;

    if (tid < 128) sq_s[tid] = sid[q0 + tid];
    const int qmin = sid[q0];
    const int qmax = sid[q0 + 127];

    // prune K-tiles outside this Q-tile's segment range (sid sorted)
    bool need = false;
    if (lane < 32) {
        int kmn = sid[lane * 64];
        int kmx = sid[lane * 64 + 63];
        need = (kmn <= qmax) && (kmx >= qmin);
    }
    unsigned long long bmask = __ballot(need);
    const int t0 = __builtin_ctzll(bmask);
    const int t1 = 64 - __builtin_clzll(bmask);

    // stage K/V tile t into buffer buf: 512 threads x 16B = one full 8KB tile
    // each for K and V (swizzled global source -> linear LDS dest).
    auto stage = [&](int buf, int t) {
        int row = tid >> 3;                    // 0..63
        int jg = (tid & 7) ^ (row & 7);
        async_copy16(kt + base + (size_t)(t * 64 + row) * DHh + jg * 8,
                     &Ks[buf][tid * 8]);
        async_copy16(vtt + base_v + (size_t)row * Ls + t * 64 + jg * 8,
                     &Vs[buf][tid * 8]);
    };

    stage(0, t0);
    const int qrow = q0 + w * 16 + l15;
    const bf16x8 a0 = *(const bf16x8*)(qt + base + (size_t)qrow * DHh + quad * 8);
    const bf16x8 a1 = *(const bf16x8*)(qt + base + (size_t)qrow * DHh + 32 + quad * 8);

    int sqv[4];
    float lsum[4] = {0.f, 0.f, 0.f, 0.f};
    f32x4 O[4];
#pragma unroll
    for (int r = 0; r < 4; ++r) O[r] = f32x4{0.f, 0.f, 0.f, 0.f};

    __syncthreads();   // drains stage(t0) + publishes sq_s
#pragma unroll
    for (int r = 0; r < 4; ++r) sqv[r] = sq_s[w * 16 + quad * 4 + r];

    for (int t = t0; t < t1; ++t) {
        const int cur = (t - t0) & 1;
        if (t + 1 < t1) stage(cur ^ 1, t + 1);   // prefetch next tile, no wait
        const int k0 = t * 64;

        // QK^T from Ks[cur]
        f32x4 s[4];
#pragma unroll
        for (int kg = 0; kg < 4; ++kg) {
            int krow = kg * 16 + l15;
            bf16x8 b0 = *(const bf16x8*)&Ks[cur][krow * 64 + ((0 + quad) ^ (krow & 7)) * 8];
            bf16x8 b1 = *(const bf16x8*)&Ks[cur][krow * 64 + ((4 + quad) ^ (krow & 7)) * 8];
            f32x4 acc = {0.f, 0.f, 0.f, 0.f};
            acc = __builtin_amdgcn_mfma_f32_16x16x32_bf16(a0, b0, acc, 0, 0, 0);
            acc = __builtin_amdgcn_mfma_f32_16x16x32_bf16(a1, b1, acc, 0, 0, 0);
            s[kg] = acc;
        }

        const int kmn = sid[k0];
        const int kmx = sid[k0 + 63];
        const bool nomask = (kmn == kmx) && (qmin == qmax) && (kmn == qmin);
        if (!nomask) {
#pragma unroll
            for (int kg = 0; kg < 4; ++kg) {
                int skv = sid[k0 + kg * 16 + l15];
#pragma unroll
                for (int r = 0; r < 4; ++r)
                    if (sqv[r] != skv) s[kg][r] = -3.0e38f;
            }
        }
#pragma unroll
        for (int kg = 0; kg < 4; ++kg)
#pragma unroll
            for (int r = 0; r < 4; ++r)
                s[kg][r] = __builtin_amdgcn_exp2f(s[kg][r]);
#pragma unroll
        for (int r = 0; r < 4; ++r)
            lsum[r] += s[0][r] + s[1][r] + s[2][r] + s[3][r];

        // P -> per-wave LDS (layout transform for PV A-fragment); no barrier:
        // DS pipe is in-order within a wave, compiler inserts lgkmcnt waits.
#pragma unroll
        for (int kg = 0; kg < 4; ++kg)
#pragma unroll
            for (int r = 0; r < 4; ++r)
                Ps[w][(quad * 4 + r) * PSP + kg * 16 + l15] = (short)f2bf(s[kg][r]);

        bf16x8 pa0 = *(const bf16x8*)&Ps[w][l15 * PSP + quad * 8];
        bf16x8 pa1 = *(const bf16x8*)&Ps[w][l15 * PSP + 32 + quad * 8];
#pragma unroll
        for (int ng = 0; ng < 4; ++ng) {
            int vrow = ng * 16 + l15;
            bf16x8 vb0 = *(const bf16x8*)&Vs[cur][vrow * 64 + ((0 + quad) ^ (vrow & 7)) * 8];
            bf16x8 vb1 = *(const bf16x8*)&Vs[cur][vrow * 64 + ((4 + quad) ^ (vrow & 7)) * 8];
            O[ng] = __builtin_amdgcn_mfma_f32_16x16x32_bf16(pa0, vb0, O[ng], 0, 0, 0);
            O[ng] = __builtin_amdgcn_mfma_f32_16x16x32_bf16(pa1, vb1, O[ng], 0, 0, 0);
        }

        // single barrier per K-tile: all waves done reading buf[cur] AND the
        // prefetch DMA into buf[cur^1] drained (aged through compute).
        __syncthreads();
    }

    // row-sum reduce over the 16 l15 lanes (quad fixed = row identity)
#pragma unroll
    for (int off = 1; off < 16; off <<= 1)
#pragma unroll
        for (int r = 0; r < 4; ++r)
            lsum[r] += __shfl_xor(lsum[r], off, 64);
    float inv_l[4];
#pragma unroll
    for (int r = 0; r < 4; ++r) inv_l[r] = 1.0f / lsum[r];
#pragma unroll
    for (int ng = 0; ng < 4; ++ng)
#pragma unroll
        for (int r = 0; r < 4; ++r) {
            int q = q0 + w * 16 + quad * 4 + r;
            ctxb[((size_t)b * Ls + q) * Dd + h * DHh + ng * 16 + l15] =
                f2bf(O[ng][r] * inv_l[r]);
        }
}

// ---------------- launcher ----------------
extern "C" void kernel_launch(void* const* d_in, const int* in_sizes, int n_in,
                              void* d_out, int out_size, void* d_ws, size_t ws_size,
                              hipStream_t stream) {
    const float* x = (const float*)d_in[0];
    const int* seq_id = (const int*)d_in[1];
    const float* ln_w = (const float*)d_in[2];
    const float* ln_b = (const float*)d_in[3];
    const float* w_qkv = (const float*)d_in[4];
    const float* q_lora_a = (const float*)d_in[5];
    const float* q_lora_b = (const float*)d_in[6];
    const float* v_lora_a = (const float*)d_in[7];
    const float* v_lora_b = (const float*)d_in[8];
    const float* q_ln_w = (const float*)d_in[9];
    const float* k_ln_w = (const float*)d_in[10];
    const float* w_out = (const float*)d_in[11];
    float* out = (float*)d_out;

    const size_t SZ = (size_t)BL * Dd;        // 4M elements
    float* p = (float*)d_ws;
    float* ropec = p;          p += (size_t)Ls * 32;
    float* ropes = p;          p += (size_t)Ls * 32;
    unsigned short* ub = (unsigned short*)p;
    unsigned short* qkvb = ub; ub += 3 * SZ;  // bf16 [BL, 3D]
    unsigned short* hb = ub;   ub += SZ;      // bf16 [BL, D]
    unsigned short* qt = ub;   ub += SZ;      // bf16 [B,H,L,DH] (prescaled)
    unsigned short* kt = ub;   ub += SZ;
    unsigned short* vtt = ub;  ub += SZ;      // bf16 [B,H,DH,L]
    unsigned short* ctxb = ub; ub += SZ;      // bf16 [BL, D]
    unsigned short* wqkvb = ub; ub += (size_t)3 * Dd * Dd;
    unsigned short* woutb = ub; ub += (size_t)Dd * Dd;

    prep_ln_kernel<<<4 * Dd + 256 + BL / 4, 256, 0, stream>>>(
        w_qkv, q_lora_a, q_lora_b, v_lora_a, v_lora_b, w_out,
        x, ln_w, ln_b, wqkvb, woutb, ropec, ropes, hb);
    {
        dim3 g(3 * Dd / 256, BL / 256);   // 12 x 16 = 192 blocks
        gemm_qkv_256<<<g, 512, 0, stream>>>(hb, wqkvb, qkvb, BL, 3 * Dd, Dd);
    }
    qkv_final_kernel<<<BL / 4 + 1024, 256, 0, stream>>>(qkvb, q_ln_w, k_ln_w,
                                                        ropec, ropes, qt, kt, vtt);
    attn_kernel<<<512, 512, 0, stream>>>(qt, kt, vtt, seq_id, ctxb);
    {
        dim3 g(Dd / 64, BL / 128);
        gemm_bt_mfma_n64<<<g, 256, 0, stream>>>(ctxb, woutb, out, BL, Dd, Dd);
    }
}

// Round 9
// 195.862 us; speedup vs baseline: 1.1362x; 1.0290x over previous
//
#include <hip/hip_runtime.h>
#include <hip/hip_bf16.h>
#include <cmath>

// Problem constants (fixed by reference)
constexpr int Bb = 2;
constexpr int Ls = 2048;
constexpr int Dd = 1024;
constexpr int Hh = 16;
constexpr int DHh = 64;
constexpr int Rr = 32;
constexpr int BL = Bb * Ls;          // 4096
constexpr float LORA_SCALE = 2.0f;   // 64/32
constexpr float LN_EPS = 1e-5f;
constexpr float ATTN_SCALE = 0.125f; // 1/sqrt(64)
constexpr float LOG2E = 1.4426950408889634f;
constexpr float QSCL = ATTN_SCALE * LOG2E;  // folded into qt

typedef __attribute__((ext_vector_type(8))) short bf16x8;
typedef __attribute__((ext_vector_type(4))) float f32x4;

__device__ __forceinline__ unsigned short f2bf(float f) {
    __hip_bfloat16 b = __float2bfloat16(f);
    return *reinterpret_cast<unsigned short*>(&b);
}
__device__ __forceinline__ float bf2f(unsigned short u) {
    unsigned int x = ((unsigned int)u) << 16;
    return __uint_as_float(x);
}
__device__ __forceinline__ void async_copy16(const void* g, void* l) {
    __builtin_amdgcn_global_load_lds(
        (__attribute__((address_space(1))) void*)(void*)(size_t)g,
        (__attribute__((address_space(3))) void*)l, 16, 0, 0);
}

// ---------------- 0. fused prep: merge-wqkv(4 rows/blk) | cast | rope | ln_x --
// grid: [0,768) merge 4 e-rows each (A-matrix L2 traffic /4 vs 1-row blocks),
// [768,1792) cast w_out, [1792,2048) rope, [2048,3072) ln_x (wave-per-row).
__global__ __launch_bounds__(256) void prep_ln_kernel(const float* __restrict__ w,
                                                      const float* __restrict__ qa,
                                                      const float* __restrict__ qb,
                                                      const float* __restrict__ va,
                                                      const float* __restrict__ vb,
                                                      const float* __restrict__ wout,
                                                      const float* __restrict__ x,
                                                      const float* __restrict__ lnw,
                                                      const float* __restrict__ lnb,
                                                      unsigned short* __restrict__ wqkvb,
                                                      unsigned short* __restrict__ woutb,
                                                      float* __restrict__ ropec,
                                                      float* __restrict__ ropes,
                                                      unsigned short* __restrict__ hb) {
    const int blk = blockIdx.x;
    const int tid = threadIdx.x;
    if (blk < 768) {
        const int e0 = blk * 4;            // 4 consecutive rows, same q/k/v region
        const int d0 = tid * 4;
        __shared__ float br[4][Rr];
        const bool isq = (e0 < Dd);
        const bool isv = (e0 >= 2 * Dd);
        const float* bsrc = isq ? (qb + (size_t)e0 * Rr)
                                : (isv ? (vb + (size_t)(e0 - 2 * Dd) * Rr) : nullptr);
        const float* asrc = isq ? qa : va;
        if (bsrc && tid < 4 * Rr) ((float*)br)[tid] = bsrc[tid];  // 4x32 contiguous
        __syncthreads();
        float acc[4][4] = {{0.f, 0.f, 0.f, 0.f}, {0.f, 0.f, 0.f, 0.f},
                           {0.f, 0.f, 0.f, 0.f}, {0.f, 0.f, 0.f, 0.f}};
        if (bsrc) {
#pragma unroll 8
            for (int r = 0; r < Rr; ++r) {
                float4 av = *(const float4*)(asrc + (size_t)r * Dd + d0);
#pragma unroll
                for (int e = 0; e < 4; ++e) {
                    float bv = br[e][r];
                    acc[e][0] += bv * av.x; acc[e][1] += bv * av.y;
                    acc[e][2] += bv * av.z; acc[e][3] += bv * av.w;
                }
            }
        }
#pragma unroll
        for (int e = 0; e < 4; ++e) {
            float4 wv = *(const float4*)(w + (size_t)(e0 + e) * Dd + d0);
            ushort4 o;
            o.x = f2bf(wv.x + LORA_SCALE * acc[e][0]);
            o.y = f2bf(wv.y + LORA_SCALE * acc[e][1]);
            o.z = f2bf(wv.z + LORA_SCALE * acc[e][2]);
            o.w = f2bf(wv.w + LORA_SCALE * acc[e][3]);
            *(ushort4*)(wqkvb + (size_t)(e0 + e) * Dd + d0) = o;
        }
    } else if (blk < 1792) {
        int i = ((blk - 768) * 256 + tid) * 4;
        float4 v = *(const float4*)(wout + i);
        ushort4 o;
        o.x = f2bf(v.x); o.y = f2bf(v.y); o.z = f2bf(v.z); o.w = f2bf(v.w);
        *(ushort4*)(woutb + i) = o;
    } else if (blk < 2048) {
        int i = (blk - 1792) * 256 + tid;    // over Ls*32
        int l = i >> 5;
        int f = i & 31;
        float invf = powf(10000.0f, -(float)f * (1.0f / 32.0f));
        float ang = (float)l * invf;
        float s, c;
        sincosf(ang, &s, &c);
        ropec[i] = c;
        ropes[i] = s;
    } else {
        // ---- LayerNorm(x): wave-per-row, no barriers ----
        const int w64 = tid >> 6;
        const int L = tid & 63;
        const int row = (blk - 2048) * 4 + w64;
        const float* xr = x + (size_t)row * Dd;
        float4 v4[4];
        float v[16];
#pragma unroll
        for (int c = 0; c < 4; ++c) {
            v4[c] = *(const float4*)(xr + c * 256 + L * 4);
            v[c * 4 + 0] = v4[c].x; v[c * 4 + 1] = v4[c].y;
            v[c * 4 + 2] = v4[c].z; v[c * 4 + 3] = v4[c].w;
        }
        float s = 0.f;
#pragma unroll
        for (int j = 0; j < 16; ++j) s += v[j];
#pragma unroll
        for (int off = 1; off < 64; off <<= 1) s += __shfl_xor(s, off, 64);
        float mean = s * (1.0f / Dd);
        float sq = 0.f;
#pragma unroll
        for (int j = 0; j < 16; ++j) {
            v[j] -= mean;
            sq += v[j] * v[j];
        }
#pragma unroll
        for (int off = 1; off < 64; off <<= 1) sq += __shfl_xor(sq, off, 64);
        float rs = rsqrtf(sq * (1.0f / Dd) + LN_EPS);
        unsigned short* hr = hb + (size_t)row * Dd;
#pragma unroll
        for (int c = 0; c < 4; ++c) {
            int d = c * 256 + L * 4;
            float4 wv = *(const float4*)(lnw + d);
            float4 bv = *(const float4*)(lnb + d);
            ushort4 o;
            o.x = f2bf(v[c * 4 + 0] * rs * wv.x + bv.x);
            o.y = f2bf(v[c * 4 + 1] * rs * wv.y + bv.y);
            o.z = f2bf(v[c * 4 + 2] * rs * wv.z + bv.z);
            o.w = f2bf(v[c * 4 + 3] * rs * wv.w + bv.w);
            *(ushort4*)(hr + d) = o;
        }
    }
}

// ---------------- 2. MFMA GEMM 256x192, 8-wave, 4-phase interleave (QKV) -----
// r8's verified 4-phase schedule, tile 256x192 -> grid 16x16 = 256 blocks
// (was 192: 25% of CUs idle). Per wave: 128 rows x 48 cols (8 mi x 3 ni).
// LDS = 64KB(A dbuf) + 48KB(B dbuf) = 112KB. One vmcnt(0)/K-tile at P4;
// stage(t+1) always targets dbuf[cur^1] (race-free, aged >=2 phases).
constexpr int GTILES = 16;   // K=1024 / BK=64

__global__ __launch_bounds__(512, 2) void gemm_qkv_256(const unsigned short* __restrict__ A,
                                                       const unsigned short* __restrict__ B,
                                                       unsigned short* __restrict__ C,
                                                       int M, int N, int K) {
    __shared__ short As[2][256 * 64];
    __shared__ short Bs[2][192 * 64];
    const int tid = threadIdx.x;
    const int w = tid >> 6;          // 0..7
    const int lane = tid & 63;
    const int quad = lane >> 4, l15 = lane & 15;
    const int wr = w >> 2;           // 0..1  (M half: 128 rows)
    const int wc = w & 3;            // 0..3  (N: 48 cols each)
    // XCD-bijective swizzle over 256 blocks (256 % 8 == 0)
    int id = blockIdx.y * 16 + blockIdx.x;
    id = (id & 7) * 32 + (id >> 3);
    const int m0 = (id >> 4) * 256;
    const int n0 = (id & 15) * 192;

    f32x4 acc[8][3];
#pragma unroll
    for (int i = 0; i < 8; ++i)
#pragma unroll
        for (int j = 0; j < 3; ++j) acc[i][j] = f32x4{0.f, 0.f, 0.f, 0.f};

    auto stageA = [&](int buf, int kt) {
#pragma unroll
        for (int i = 0; i < 4; ++i) {
            int c = tid + i * 512;            // 0..2047
            int row = c >> 3;                 // 0..255
            int jg = (c & 7) ^ (row & 7);
            async_copy16(A + (size_t)(m0 + row) * K + kt * 64 + jg * 8,
                         &As[buf][c * 8]);
        }
    };
    auto stageB = [&](int buf, int kt) {
#pragma unroll
        for (int i = 0; i < 3; ++i) {
            int c = tid + i * 512;            // 0..1535
            int row = c >> 3;                 // 0..191
            int jg = (c & 7) ^ (row & 7);
            async_copy16(B + (size_t)(n0 + row) * K + kt * 64 + jg * 8,
                         &Bs[buf][c * 8]);
        }
    };

    stageA(0, 0);
    stageB(0, 0);
    asm volatile("s_waitcnt vmcnt(0)");
    asm volatile("" ::: "memory");
    __builtin_amdgcn_s_barrier();

    for (int t = 0; t < GTILES; ++t) {
        const int cur = t & 1;
        const short* as = As[cur];
        const short* bs = Bs[cur];
        bf16x8 af[8], bfr[2];

        // ---- P1: A frags ks=0 (8 dsr) + B ni=0,1 ks=0 (2 dsr) | stage A(t+1)
#pragma unroll
        for (int mi = 0; mi < 8; ++mi) {
            int row = wr * 128 + mi * 16 + l15;
            af[mi] = *(const bf16x8*)&as[row * 64 + ((0 + quad) ^ (row & 7)) * 8];
        }
#pragma unroll
        for (int ni = 0; ni < 2; ++ni) {
            int row = wc * 48 + ni * 16 + l15;
            bfr[ni] = *(const bf16x8*)&bs[row * 64 + ((0 + quad) ^ (row & 7)) * 8];
        }
        if (t + 1 < GTILES) stageA(cur ^ 1, t + 1);
        asm volatile("" ::: "memory");
        __builtin_amdgcn_s_barrier();
        asm volatile("s_waitcnt lgkmcnt(0)");
        __builtin_amdgcn_s_setprio(1);
#pragma unroll
        for (int mi = 0; mi < 8; ++mi)
#pragma unroll
            for (int ni = 0; ni < 2; ++ni)
                acc[mi][ni] = __builtin_amdgcn_mfma_f32_16x16x32_bf16(af[mi], bfr[ni], acc[mi][ni], 0, 0, 0);
        __builtin_amdgcn_s_setprio(0);
        asm volatile("" ::: "memory");
        __builtin_amdgcn_s_barrier();

        // ---- P2: B ni=2 ks=0 (1 dsr) | stage B(t+1)
        {
            int row = wc * 48 + 2 * 16 + l15;
            bfr[0] = *(const bf16x8*)&bs[row * 64 + ((0 + quad) ^ (row & 7)) * 8];
        }
        if (t + 1 < GTILES) stageB(cur ^ 1, t + 1);
        asm volatile("" ::: "memory");
        __builtin_amdgcn_s_barrier();
        asm volatile("s_waitcnt lgkmcnt(0)");
        __builtin_amdgcn_s_setprio(1);
#pragma unroll
        for (int mi = 0; mi < 8; ++mi)
            acc[mi][2] = __builtin_amdgcn_mfma_f32_16x16x32_bf16(af[mi], bfr[0], acc[mi][2], 0, 0, 0);
        __builtin_amdgcn_s_setprio(0);
        asm volatile("" ::: "memory");
        __builtin_amdgcn_s_barrier();

        // ---- P3: A frags ks=1 (8 dsr) + B ni=0,1 ks=1 (2 dsr)
#pragma unroll
        for (int mi = 0; mi < 8; ++mi) {
            int row = wr * 128 + mi * 16 + l15;
            af[mi] = *(const bf16x8*)&as[row * 64 + ((4 + quad) ^ (row & 7)) * 8];
        }
#pragma unroll
        for (int ni = 0; ni < 2; ++ni) {
            int row = wc * 48 + ni * 16 + l15;
            bfr[ni] = *(const bf16x8*)&bs[row * 64 + ((4 + quad) ^ (row & 7)) * 8];
        }
        asm volatile("" ::: "memory");
        __builtin_amdgcn_s_barrier();
        asm volatile("s_waitcnt lgkmcnt(0)");
        __builtin_amdgcn_s_setprio(1);
#pragma unroll
        for (int mi = 0; mi < 8; ++mi)
#pragma unroll
            for (int ni = 0; ni < 2; ++ni)
                acc[mi][ni] = __builtin_amdgcn_mfma_f32_16x16x32_bf16(af[mi], bfr[ni], acc[mi][ni], 0, 0, 0);
        __builtin_amdgcn_s_setprio(0);
        asm volatile("" ::: "memory");
        __builtin_amdgcn_s_barrier();

        // ---- P4: B ni=2 ks=1 (1 dsr) | vmcnt(0) drains stage(t+1)
        {
            int row = wc * 48 + 2 * 16 + l15;
            bfr[0] = *(const bf16x8*)&bs[row * 64 + ((4 + quad) ^ (row & 7)) * 8];
        }
        asm volatile("s_waitcnt vmcnt(0)");
        asm volatile("" ::: "memory");
        __builtin_amdgcn_s_barrier();
        asm volatile("s_waitcnt lgkmcnt(0)");
        __builtin_amdgcn_s_setprio(1);
#pragma unroll
        for (int mi = 0; mi < 8; ++mi)
            acc[mi][2] = __builtin_amdgcn_mfma_f32_16x16x32_bf16(af[mi], bfr[0], acc[mi][2], 0, 0, 0);
        __builtin_amdgcn_s_setprio(0);
        asm volatile("" ::: "memory");
        __builtin_amdgcn_s_barrier();
    }

#pragma unroll
    for (int mi = 0; mi < 8; ++mi)
#pragma unroll
        for (int ni = 0; ni < 3; ++ni)
#pragma unroll
            for (int r = 0; r < 4; ++r)
                C[(size_t)(m0 + wr * 128 + mi * 16 + quad * 4 + r) * N +
                  n0 + wc * 48 + ni * 16 + l15] = f2bf(acc[mi][ni][r]);
}

// ---------------- 2b. MFMA GEMM 128x64 tile (fp32 out) — out-projection -------
// (n64 kept: 512 blocks = 2/CU beat the 128^2 f32 variant by ~8us in r7.
//  XCD-bijective swizzle added: 512 % 8 == 0.)
__global__ __launch_bounds__(256) void gemm_bt_mfma_n64(const unsigned short* __restrict__ A,
                                                        const unsigned short* __restrict__ B,
                                                        float* __restrict__ C,
                                                        int M, int N, int K) {
    __shared__ short As[128 * 64];
    __shared__ short Bs[64 * 64];
    const int tid = threadIdx.x;
    const int w = tid >> 6, lane = tid & 63, quad = lane >> 4, l15 = lane & 15;
    int id = blockIdx.y * 16 + blockIdx.x;   // grid (16, 32) -> 512 blocks
    id = (id & 7) * 64 + (id >> 3);
    const int m0 = (id >> 4) * 128, n0 = (id & 15) * 64;
    const int wm = (w & 1) * 64, wn = (w >> 1) * 32;
    f32x4 acc[4][2];
#pragma unroll
    for (int i = 0; i < 4; ++i)
#pragma unroll
        for (int j = 0; j < 2; ++j) acc[i][j] = f32x4{0.f, 0.f, 0.f, 0.f};

    for (int k0 = 0; k0 < K; k0 += 64) {
#pragma unroll
        for (int j = 0; j < 4; ++j) {
            int c = tid + j * 256;
            int row = c >> 3;
            int jg = (c & 7) ^ (row & 7);
            async_copy16(A + (size_t)(m0 + row) * K + k0 + jg * 8, As + c * 8);
        }
#pragma unroll
        for (int j = 0; j < 2; ++j) {
            int c = tid + j * 256;
            int row = c >> 3;
            int jg = (c & 7) ^ (row & 7);
            async_copy16(B + (size_t)(n0 + row) * K + k0 + jg * 8, Bs + c * 8);
        }
        __syncthreads();
#pragma unroll
        for (int ks = 0; ks < 2; ++ks) {
            bf16x8 a[4], b[2];
#pragma unroll
            for (int mi = 0; mi < 4; ++mi) {
                int row = wm + mi * 16 + l15;
                int ch = (ks * 4 + quad) ^ (row & 7);
                a[mi] = *(const bf16x8*)&As[row * 64 + ch * 8];
            }
#pragma unroll
            for (int ni = 0; ni < 2; ++ni) {
                int row = wn + ni * 16 + l15;
                int ch = (ks * 4 + quad) ^ (row & 7);
                b[ni] = *(const bf16x8*)&Bs[row * 64 + ch * 8];
            }
#pragma unroll
            for (int mi = 0; mi < 4; ++mi)
#pragma unroll
                for (int ni = 0; ni < 2; ++ni)
                    acc[mi][ni] = __builtin_amdgcn_mfma_f32_16x16x32_bf16(a[mi], b[ni], acc[mi][ni], 0, 0, 0);
        }
        __syncthreads();
    }
#pragma unroll
    for (int mi = 0; mi < 4; ++mi)
#pragma unroll
        for (int ni = 0; ni < 2; ++ni)
#pragma unroll
            for (int r = 0; r < 4; ++r)
                C[(size_t)(m0 + wm + mi * 16 + quad * 4 + r) * N + n0 + wn + ni * 16 + l15] =
                    acc[mi][ni][r];
}

// ---------------- 3. fused Q/K finalize (wave-per-row) + V transpose ----------
__global__ __launch_bounds__(256) void qkv_final_kernel(const unsigned short* __restrict__ qkvb,
                                                        const float* __restrict__ qlnw,
                                                        const float* __restrict__ klnw,
                                                        const float* __restrict__ ropec,
                                                        const float* __restrict__ ropes,
                                                        unsigned short* __restrict__ qt,
                                                        unsigned short* __restrict__ kt,
                                                        unsigned short* __restrict__ vtt) {
    const int blk = blockIdx.x;
    const int tid = threadIdx.x;
    if (blk < BL / 4) {
        const int w64 = tid >> 6;
        const int L = tid & 63;
        const int row = blk * 4 + w64;
        const int b = row >> 11;
        const int l = row & (Ls - 1);
        const unsigned short* qp = qkvb + (size_t)row * (3 * Dd);
        const unsigned short* kp = qp + Dd;

        bf16x8 qA = *(const bf16x8*)(qp + L * 8);
        bf16x8 qB = *(const bf16x8*)(qp + 512 + L * 8);
        bf16x8 kA = *(const bf16x8*)(kp + L * 8);
        bf16x8 kB = *(const bf16x8*)(kp + 512 + L * 8);
        float vq[16], vk[16];
#pragma unroll
        for (int j = 0; j < 8; ++j) {
            vq[j] = bf2f((unsigned short)qA[j]);
            vq[8 + j] = bf2f((unsigned short)qB[j]);
            vk[j] = bf2f((unsigned short)kA[j]);
            vk[8 + j] = bf2f((unsigned short)kB[j]);
        }
        float sq = 0.f, sk = 0.f;
#pragma unroll
        for (int j = 0; j < 16; ++j) { sq += vq[j]; sk += vk[j]; }
#pragma unroll
        for (int off = 1; off < 64; off <<= 1) {
            sq += __shfl_xor(sq, off, 64);
            sk += __shfl_xor(sk, off, 64);
        }
        float mq = sq * (1.0f / Dd), mk = sk * (1.0f / Dd);
        float vvq = 0.f, vvk = 0.f;
#pragma unroll
        for (int j = 0; j < 16; ++j) {
            vq[j] -= mq; vvq += vq[j] * vq[j];
            vk[j] -= mk; vvk += vk[j] * vk[j];
        }
#pragma unroll
        for (int off = 1; off < 64; off <<= 1) {
            vvq += __shfl_xor(vvq, off, 64);
            vvk += __shfl_xor(vvk, off, 64);
        }
        float rsq = rsqrtf(vvq * (1.0f / Dd) + LN_EPS);
        float rsk = rsqrtf(vvk * (1.0f / Dd) + LN_EPS);

        float yq[16], yk[16];
        {
            float4 w0 = *(const float4*)(qlnw + L * 8);
            float4 w1 = *(const float4*)(qlnw + L * 8 + 4);
            float4 w2 = *(const float4*)(qlnw + 512 + L * 8);
            float4 w3 = *(const float4*)(qlnw + 512 + L * 8 + 4);
            yq[0] = vq[0] * rsq * w0.x; yq[1] = vq[1] * rsq * w0.y;
            yq[2] = vq[2] * rsq * w0.z; yq[3] = vq[3] * rsq * w0.w;
            yq[4] = vq[4] * rsq * w1.x; yq[5] = vq[5] * rsq * w1.y;
            yq[6] = vq[6] * rsq * w1.z; yq[7] = vq[7] * rsq * w1.w;
            yq[8] = vq[8] * rsq * w2.x; yq[9] = vq[9] * rsq * w2.y;
            yq[10] = vq[10] * rsq * w2.z; yq[11] = vq[11] * rsq * w2.w;
            yq[12] = vq[12] * rsq * w3.x; yq[13] = vq[13] * rsq * w3.y;
            yq[14] = vq[14] * rsq * w3.z; yq[15] = vq[15] * rsq * w3.w;
        }
        {
            float4 w0 = *(const float4*)(klnw + L * 8);
            float4 w1 = *(const float4*)(klnw + L * 8 + 4);
            float4 w2 = *(const float4*)(klnw + 512 + L * 8);
            float4 w3 = *(const float4*)(klnw + 512 + L * 8 + 4);
            yk[0] = vk[0] * rsk * w0.x; yk[1] = vk[1] * rsk * w0.y;
            yk[2] = vk[2] * rsk * w0.z; yk[3] = vk[3] * rsk * w0.w;
            yk[4] = vk[4] * rsk * w1.x; yk[5] = vk[5] * rsk * w1.y;
            yk[6] = vk[6] * rsk * w1.z; yk[7] = vk[7] * rsk * w1.w;
            yk[8] = vk[8] * rsk * w2.x; yk[9] = vk[9] * rsk * w2.y;
            yk[10] = vk[10] * rsk * w2.z; yk[11] = vk[11] * rsk * w2.w;
            yk[12] = vk[12] * rsk * w3.x; yk[13] = vk[13] * rsk * w3.y;
            yk[14] = vk[14] * rsk * w3.z; yk[15] = vk[15] * rsk * w3.w;
        }

        float cs[8], sn[8];
        {
            int fbase = l * 32 + (L & 3) * 8;
            float4 c0 = *(const float4*)(ropec + fbase);
            float4 c1 = *(const float4*)(ropec + fbase + 4);
            float4 s0 = *(const float4*)(ropes + fbase);
            float4 s1 = *(const float4*)(ropes + fbase + 4);
            cs[0] = c0.x; cs[1] = c0.y; cs[2] = c0.z; cs[3] = c0.w;
            cs[4] = c1.x; cs[5] = c1.y; cs[6] = c1.z; cs[7] = c1.w;
            sn[0] = s0.x; sn[1] = s0.y; sn[2] = s0.z; sn[3] = s0.w;
            sn[4] = s1.x; sn[5] = s1.y; sn[6] = s1.z; sn[7] = s1.w;
        }
        const float sgn = (L & 4) ? 1.0f : -1.0f;  // dh>=32 ? + : -
        unsigned short outqA[8], outqB[8], outkA[8], outkB[8];
#pragma unroll
        for (int j = 0; j < 8; ++j) {
            float pA = __shfl_xor(yq[j], 4, 64);
            float pB = __shfl_xor(yq[8 + j], 4, 64);
            outqA[j] = f2bf((yq[j] * cs[j] + sgn * pA * sn[j]) * QSCL);
            outqB[j] = f2bf((yq[8 + j] * cs[j] + sgn * pB * sn[j]) * QSCL);
            float pkA = __shfl_xor(yk[j], 4, 64);
            float pkB = __shfl_xor(yk[8 + j], 4, 64);
            outkA[j] = f2bf(yk[j] * cs[j] + sgn * pkA * sn[j]);
            outkB[j] = f2bf(yk[8 + j] * cs[j] + sgn * pkB * sn[j]);
        }
        const int hA = L >> 3;
        const int dh0 = (L & 7) * 8;
        size_t offA = (((size_t)(b * Hh + hA)) * Ls + l) * DHh + dh0;
        size_t offB = (((size_t)(b * Hh + 8 + hA)) * Ls + l) * DHh + dh0;
        *(uint4*)(qt + offA) = *(uint4*)outqA;
        *(uint4*)(qt + offB) = *(uint4*)outqB;
        *(uint4*)(kt + offA) = *(uint4*)outkA;
        *(uint4*)(kt + offB) = *(uint4*)outkB;
    } else {
        // ---- V transpose tile ----
        const int t2 = blk - BL / 4;           // 0..1023
        const int l0 = (t2 & 31) * 64;
        const int h = (t2 >> 5) & 15;
        const int b = t2 >> 9;
        __shared__ short t[64][72];
        const unsigned short* src = qkvb + (size_t)b * Ls * (3 * Dd) + 2 * Dd + h * 64;
#pragma unroll
        for (int j = 0; j < 2; ++j) {
            int g = tid + j * 256;
            int row = g >> 3;
            int c0 = (g & 7) * 8;
            uint4 vv = *(const uint4*)(src + (size_t)(l0 + row) * (3 * Dd) + c0);
            *(uint4*)&t[row][c0] = vv;
        }
        __syncthreads();
        unsigned short* dst = vtt + ((size_t)(b * Hh + h) * DHh) * Ls;
#pragma unroll
        for (int j = 0; j < 2; ++j) {
            int g = tid + j * 256;
            int dh = g >> 3;
            int lc = (g & 7) * 8;
            ushort4 o0, o1;
            unsigned short* p0 = (unsigned short*)&o0;
            unsigned short* p1 = (unsigned short*)&o1;
#pragma unroll
            for (int i = 0; i < 4; ++i) p0[i] = (unsigned short)t[lc + i][dh];
#pragma unroll
            for (int i = 0; i < 4; ++i) p1[i] = (unsigned short)t[lc + 4 + i][dh];
            *(ushort4*)(dst + (size_t)dh * Ls + l0 + lc) = o0;
            *(ushort4*)(dst + (size_t)dh * Ls + l0 + lc + 4) = o1;
        }
    }
}

// ---------------- 5. MFMA flash attention — Q=128, 8 waves, dbuf pipeline ----
// (round-3 configuration: session-best attn)
constexpr int PSP = 76;  // Ps pitch (bank-conflict-free, measured 0 conflicts)

__global__ __launch_bounds__(512) void attn_kernel(const unsigned short* __restrict__ qt,
                                                   const unsigned short* __restrict__ kt,
                                                   const unsigned short* __restrict__ vtt,
                                                   const int* __restrict__ seq_id,
                                                   unsigned short* __restrict__ ctxb) {
    const int id = blockIdx.x;            // 0..511
    const int c8 = id & 7;                // XCD-swizzle: h%8 pinned per XCD
    const int x = (id >> 3) & 15;
    const int g4 = id >> 7;               // 0..3
    const int v = c8 + 8 * g4;            // h + 16*b
    const int b = v >> 4;
    const int h = v & 15;
    const int q0 = x * 128;

    const size_t base = ((size_t)(b * Hh + h)) * Ls * DHh;
    const size_t base_v = ((size_t)(b * Hh + h)) * DHh * Ls;
    const int* sid = seq_id + (size_t)b * Ls;

    __shared__ short Ks[2][64 * 64];
    __shared__ short Vs[2][64 * 64];
    __shared__ short Ps[8][16 * PSP];
    __shared__ int sq_s[128];

    const int tid = threadIdx.x;
    const int w = tid >> 6;               // 0..7
    const int lane = tid & 63;
    const int quad = lane >> 4;
    const int l15 = lane & 15;

    if (tid < 128) sq_s[tid] = sid[q0 + tid];
    const int qmin = sid[q0];
    const int qmax = sid[q0 + 127];

    // prune K-tiles outside this Q-tile's segment range (sid sorted)
    bool need = false;
    if (lane < 32) {
        int kmn = sid[lane * 64];
        int kmx = sid[lane * 64 + 63];
        need = (kmn <= qmax) && (kmx >= qmin);
    }
    unsigned long long bmask = __ballot(need);
    const int t0 = __builtin_ctzll(bmask);
    const int t1 = 64 - __builtin_clzll(bmask);

    // stage K/V tile t into buffer buf: 512 threads x 16B = one full 8KB tile
    // each for K and V (swizzled global source -> linear LDS dest).
    auto stage = [&](int buf, int t) {
        int row = tid >> 3;                    // 0..63
        int jg = (tid & 7) ^ (row & 7);
        async_copy16(kt + base + (size_t)(t * 64 + row) * DHh + jg * 8,
                     &Ks[buf][tid * 8]);
        async_copy16(vtt + base_v + (size_t)row * Ls + t * 64 + jg * 8,
                     &Vs[buf][tid * 8]);
    };

    stage(0, t0);
    const int qrow = q0 + w * 16 + l15;
    const bf16x8 a0 = *(const bf16x8*)(qt + base + (size_t)qrow * DHh + quad * 8);
    const bf16x8 a1 = *(const bf16x8*)(qt + base + (size_t)qrow * DHh + 32 + quad * 8);

    int sqv[4];
    float lsum[4] = {0.f, 0.f, 0.f, 0.f};
    f32x4 O[4];
#pragma unroll
    for (int r = 0; r < 4; ++r) O[r] = f32x4{0.f, 0.f, 0.f, 0.f};

    __syncthreads();   // drains stage(t0) + publishes sq_s
#pragma unroll
    for (int r = 0; r < 4; ++r) sqv[r] = sq_s[w * 16 + quad * 4 + r];

    for (int t = t0; t < t1; ++t) {
        const int cur = (t - t0) & 1;
        if (t + 1 < t1) stage(cur ^ 1, t + 1);   // prefetch next tile, no wait
        const int k0 = t * 64;

        // QK^T from Ks[cur]
        f32x4 s[4];
#pragma unroll
        for (int kg = 0; kg < 4; ++kg) {
            int krow = kg * 16 + l15;
            bf16x8 b0 = *(const bf16x8*)&Ks[cur][krow * 64 + ((0 + quad) ^ (krow & 7)) * 8];
            bf16x8 b1 = *(const bf16x8*)&Ks[cur][krow * 64 + ((4 + quad) ^ (krow & 7)) * 8];
            f32x4 acc = {0.f, 0.f, 0.f, 0.f};
            acc = __builtin_amdgcn_mfma_f32_16x16x32_bf16(a0, b0, acc, 0, 0, 0);
            acc = __builtin_amdgcn_mfma_f32_16x16x32_bf16(a1, b1, acc, 0, 0, 0);
            s[kg] = acc;
        }

        const int kmn = sid[k0];
        const int kmx = sid[k0 + 63];
        const bool nomask = (kmn == kmx) && (qmin == qmax) && (kmn == qmin);
        if (!nomask) {
#pragma unroll
            for (int kg = 0; kg < 4; ++kg) {
                int skv = sid[k0 + kg * 16 + l15];
#pragma unroll
                for (int r = 0; r < 4; ++r)
                    if (sqv[r] != skv) s[kg][r] = -3.0e38f;
            }
        }
#pragma unroll
        for (int kg = 0; kg < 4; ++kg)
#pragma unroll
            for (int r = 0; r < 4; ++r)
                s[kg][r] = __builtin_amdgcn_exp2f(s[kg][r]);
#pragma unroll
        for (int r = 0; r < 4; ++r)
            lsum[r] += s[0][r] + s[1][r] + s[2][r] + s[3][r];

        // P -> per-wave LDS (layout transform for PV A-fragment); no barrier:
        // DS pipe is in-order within a wave, compiler inserts lgkmcnt waits.
#pragma unroll
        for (int kg = 0; kg < 4; ++kg)
#pragma unroll
            for (int r = 0; r < 4; ++r)
                Ps[w][(quad * 4 + r) * PSP + kg * 16 + l15] = (short)f2bf(s[kg][r]);

        bf16x8 pa0 = *(const bf16x8*)&Ps[w][l15 * PSP + quad * 8];
        bf16x8 pa1 = *(const bf16x8*)&Ps[w][l15 * PSP + 32 + quad * 8];
#pragma unroll
        for (int ng = 0; ng < 4; ++ng) {
            int vrow = ng * 16 + l15;
            bf16x8 vb0 = *(const bf16x8*)&Vs[cur][vrow * 64 + ((0 + quad) ^ (vrow & 7)) * 8];
            bf16x8 vb1 = *(const bf16x8*)&Vs[cur][vrow * 64 + ((4 + quad) ^ (vrow & 7)) * 8];
            O[ng] = __builtin_amdgcn_mfma_f32_16x16x32_bf16(pa0, vb0, O[ng], 0, 0, 0);
            O[ng] = __builtin_amdgcn_mfma_f32_16x16x32_bf16(pa1, vb1, O[ng], 0, 0, 0);
        }

        // single barrier per K-tile: all waves done reading buf[cur] AND the
        // prefetch DMA into buf[cur^1] drained (aged through compute).
        __syncthreads();
    }

    // row-sum reduce over the 16 l15 lanes (quad fixed = row identity)
#pragma unroll
    for (int off = 1; off < 16; off <<= 1)
#pragma unroll
        for (int r = 0; r < 4; ++r)
            lsum[r] += __shfl_xor(lsum[r], off, 64);
    float inv_l[4];
#pragma unroll
    for (int r = 0; r < 4; ++r) inv_l[r] = 1.0f / lsum[r];
#pragma unroll
    for (int ng = 0; ng < 4; ++ng)
#pragma unroll
        for (int r = 0; r < 4; ++r) {
            int q = q0 + w * 16 + quad * 4 + r;
            ctxb[((size_t)b * Ls + q) * Dd + h * DHh + ng * 16 + l15] =
                f2bf(O[ng][r] * inv_l[r]);
        }
}

// ---------------- launcher ----------------
extern "C" void kernel_launch(void* const* d_in, const int* in_sizes, int n_in,
                              void* d_out, int out_size, void* d_ws, size_t ws_size,
                              hipStream_t stream) {
    const float* x = (const float*)d_in[0];
    const int* seq_id = (const int*)d_in[1];
    const float* ln_w = (const float*)d_in[2];
    const float* ln_b = (const float*)d_in[3];
    const float* w_qkv = (const float*)d_in[4];
    const float* q_lora_a = (const float*)d_in[5];
    const float* q_lora_b = (const float*)d_in[6];
    const float* v_lora_a = (const float*)d_in[7];
    const float* v_lora_b = (const float*)d_in[8];
    const float* q_ln_w = (const float*)d_in[9];
    const float* k_ln_w = (const float*)d_in[10];
    const float* w_out = (const float*)d_in[11];
    float* out = (float*)d_out;

    const size_t SZ = (size_t)BL * Dd;        // 4M elements
    float* p = (float*)d_ws;
    float* ropec = p;          p += (size_t)Ls * 32;
    float* ropes = p;          p += (size_t)Ls * 32;
    unsigned short* ub = (unsigned short*)p;
    unsigned short* qkvb = ub; ub += 3 * SZ;  // bf16 [BL, 3D]
    unsigned short* hb = ub;   ub += SZ;      // bf16 [BL, D]
    unsigned short* qt = ub;   ub += SZ;      // bf16 [B,H,L,DH] (prescaled)
    unsigned short* kt = ub;   ub += SZ;
    unsigned short* vtt = ub;  ub += SZ;      // bf16 [B,H,DH,L]
    unsigned short* ctxb = ub; ub += SZ;      // bf16 [BL, D]
    unsigned short* wqkvb = ub; ub += (size_t)3 * Dd * Dd;
    unsigned short* woutb = ub; ub += (size_t)Dd * Dd;

    prep_ln_kernel<<<3072, 256, 0, stream>>>(
        w_qkv, q_lora_a, q_lora_b, v_lora_a, v_lora_b, w_out,
        x, ln_w, ln_b, wqkvb, woutb, ropec, ropes, hb);
    {
        dim3 g(3 * Dd / 192, BL / 256);   // 16 x 16 = 256 blocks (full CU cover)
        gemm_qkv_256<<<g, 512, 0, stream>>>(hb, wqkvb, qkvb, BL, 3 * Dd, Dd);
    }
    qkv_final_kernel<<<BL / 4 + 1024, 256, 0, stream>>>(qkvb, q_ln_w, k_ln_w,
                                                        ropec, ropes, qt, kt, vtt);
    attn_kernel<<<512, 512, 0, stream>>>(qt, kt, vtt, seq_id, ctxb);
    {
        dim3 g(Dd / 64, BL / 128);
        gemm_bt_mfma_n64<<<g, 256, 0, stream>>>(ctxb, woutb, out, BL, Dd, Dd);
    }
}

// Round 10
// 191.162 us; speedup vs baseline: 1.1642x; 1.0246x over previous
//
#include <hip/hip_runtime.h>
#include <hip/hip_bf16.h>
#include <cmath>

// Problem constants (fixed by reference)
constexpr int Bb = 2;
constexpr int Ls = 2048;
constexpr int Dd = 1024;
constexpr int Hh = 16;
constexpr int DHh = 64;
constexpr int Rr = 32;
constexpr int BL = Bb * Ls;          // 4096
constexpr float LORA_SCALE = 2.0f;   // 64/32
constexpr float LN_EPS = 1e-5f;
constexpr float ATTN_SCALE = 0.125f; // 1/sqrt(64)
constexpr float LOG2E = 1.4426950408889634f;
constexpr float QSCL = ATTN_SCALE * LOG2E;  // folded into qt

typedef __attribute__((ext_vector_type(8))) short bf16x8;
typedef __attribute__((ext_vector_type(4))) float f32x4;

__device__ __forceinline__ unsigned short f2bf(float f) {
    __hip_bfloat16 b = __float2bfloat16(f);
    return *reinterpret_cast<unsigned short*>(&b);
}
__device__ __forceinline__ float bf2f(unsigned short u) {
    unsigned int x = ((unsigned int)u) << 16;
    return __uint_as_float(x);
}
__device__ __forceinline__ void async_copy16(const void* g, void* l) {
    __builtin_amdgcn_global_load_lds(
        (__attribute__((address_space(1))) void*)(void*)(size_t)g,
        (__attribute__((address_space(3))) void*)l, 16, 0, 0);
}

// ---------------- 0. fused prep: merge-wqkv(4 rows/blk) | cast | rope | ln_x --
__global__ __launch_bounds__(256) void prep_ln_kernel(const float* __restrict__ w,
                                                      const float* __restrict__ qa,
                                                      const float* __restrict__ qb,
                                                      const float* __restrict__ va,
                                                      const float* __restrict__ vb,
                                                      const float* __restrict__ wout,
                                                      const float* __restrict__ x,
                                                      const float* __restrict__ lnw,
                                                      const float* __restrict__ lnb,
                                                      unsigned short* __restrict__ wqkvb,
                                                      unsigned short* __restrict__ woutb,
                                                      float* __restrict__ ropec,
                                                      float* __restrict__ ropes,
                                                      unsigned short* __restrict__ hb) {
    const int blk = blockIdx.x;
    const int tid = threadIdx.x;
    if (blk < 768) {
        const int e0 = blk * 4;            // 4 consecutive rows, same q/k/v region
        const int d0 = tid * 4;
        __shared__ float br[4][Rr];
        const bool isq = (e0 < Dd);
        const bool isv = (e0 >= 2 * Dd);
        const float* bsrc = isq ? (qb + (size_t)e0 * Rr)
                                : (isv ? (vb + (size_t)(e0 - 2 * Dd) * Rr) : nullptr);
        const float* asrc = isq ? qa : va;
        if (bsrc && tid < 4 * Rr) ((float*)br)[tid] = bsrc[tid];  // 4x32 contiguous
        __syncthreads();
        float acc[4][4] = {{0.f, 0.f, 0.f, 0.f}, {0.f, 0.f, 0.f, 0.f},
                           {0.f, 0.f, 0.f, 0.f}, {0.f, 0.f, 0.f, 0.f}};
        if (bsrc) {
#pragma unroll 8
            for (int r = 0; r < Rr; ++r) {
                float4 av = *(const float4*)(asrc + (size_t)r * Dd + d0);
#pragma unroll
                for (int e = 0; e < 4; ++e) {
                    float bv = br[e][r];
                    acc[e][0] += bv * av.x; acc[e][1] += bv * av.y;
                    acc[e][2] += bv * av.z; acc[e][3] += bv * av.w;
                }
            }
        }
#pragma unroll
        for (int e = 0; e < 4; ++e) {
            float4 wv = *(const float4*)(w + (size_t)(e0 + e) * Dd + d0);
            ushort4 o;
            o.x = f2bf(wv.x + LORA_SCALE * acc[e][0]);
            o.y = f2bf(wv.y + LORA_SCALE * acc[e][1]);
            o.z = f2bf(wv.z + LORA_SCALE * acc[e][2]);
            o.w = f2bf(wv.w + LORA_SCALE * acc[e][3]);
            *(ushort4*)(wqkvb + (size_t)(e0 + e) * Dd + d0) = o;
        }
    } else if (blk < 1792) {
        int i = ((blk - 768) * 256 + tid) * 4;
        float4 v = *(const float4*)(wout + i);
        ushort4 o;
        o.x = f2bf(v.x); o.y = f2bf(v.y); o.z = f2bf(v.z); o.w = f2bf(v.w);
        *(ushort4*)(woutb + i) = o;
    } else if (blk < 2048) {
        int i = (blk - 1792) * 256 + tid;    // over Ls*32
        int l = i >> 5;
        int f = i & 31;
        float invf = powf(10000.0f, -(float)f * (1.0f / 32.0f));
        float ang = (float)l * invf;
        float s, c;
        sincosf(ang, &s, &c);
        ropec[i] = c;
        ropes[i] = s;
    } else {
        // ---- LayerNorm(x): wave-per-row, no barriers ----
        const int w64 = tid >> 6;
        const int L = tid & 63;
        const int row = (blk - 2048) * 4 + w64;
        const float* xr = x + (size_t)row * Dd;
        float4 v4[4];
        float v[16];
#pragma unroll
        for (int c = 0; c < 4; ++c) {
            v4[c] = *(const float4*)(xr + c * 256 + L * 4);
            v[c * 4 + 0] = v4[c].x; v[c * 4 + 1] = v4[c].y;
            v[c * 4 + 2] = v4[c].z; v[c * 4 + 3] = v4[c].w;
        }
        float s = 0.f;
#pragma unroll
        for (int j = 0; j < 16; ++j) s += v[j];
#pragma unroll
        for (int off = 1; off < 64; off <<= 1) s += __shfl_xor(s, off, 64);
        float mean = s * (1.0f / Dd);
        float sq = 0.f;
#pragma unroll
        for (int j = 0; j < 16; ++j) {
            v[j] -= mean;
            sq += v[j] * v[j];
        }
#pragma unroll
        for (int off = 1; off < 64; off <<= 1) sq += __shfl_xor(sq, off, 64);
        float rs = rsqrtf(sq * (1.0f / Dd) + LN_EPS);
        unsigned short* hr = hb + (size_t)row * Dd;
#pragma unroll
        for (int c = 0; c < 4; ++c) {
            int d = c * 256 + L * 4;
            float4 wv = *(const float4*)(lnw + d);
            float4 bv = *(const float4*)(lnb + d);
            ushort4 o;
            o.x = f2bf(v[c * 4 + 0] * rs * wv.x + bv.x);
            o.y = f2bf(v[c * 4 + 1] * rs * wv.y + bv.y);
            o.z = f2bf(v[c * 4 + 2] * rs * wv.z + bv.z);
            o.w = f2bf(v[c * 4 + 3] * rs * wv.w + bv.w);
            *(ushort4*)(hr + d) = o;
        }
    }
}

// ---------------- 2. MFMA GEMM 256x192, 8-wave, 4-phase interleave (QKV) -----
// (r9-verified: grid 16x16 = 256 blocks, one vmcnt(0)/K-tile, XCD swizzle)
constexpr int GTILES = 16;   // K=1024 / BK=64

__global__ __launch_bounds__(512, 2) void gemm_qkv_256(const unsigned short* __restrict__ A,
                                                       const unsigned short* __restrict__ B,
                                                       unsigned short* __restrict__ C,
                                                       int M, int N, int K) {
    __shared__ short As[2][256 * 64];
    __shared__ short Bs[2][192 * 64];
    const int tid = threadIdx.x;
    const int w = tid >> 6;          // 0..7
    const int lane = tid & 63;
    const int quad = lane >> 4, l15 = lane & 15;
    const int wr = w >> 2;           // 0..1  (M half: 128 rows)
    const int wc = w & 3;            // 0..3  (N: 48 cols each)
    // XCD-bijective swizzle over 256 blocks (256 % 8 == 0)
    int id = blockIdx.y * 16 + blockIdx.x;
    id = (id & 7) * 32 + (id >> 3);
    const int m0 = (id >> 4) * 256;
    const int n0 = (id & 15) * 192;

    f32x4 acc[8][3];
#pragma unroll
    for (int i = 0; i < 8; ++i)
#pragma unroll
        for (int j = 0; j < 3; ++j) acc[i][j] = f32x4{0.f, 0.f, 0.f, 0.f};

    auto stageA = [&](int buf, int kt) {
#pragma unroll
        for (int i = 0; i < 4; ++i) {
            int c = tid + i * 512;            // 0..2047
            int row = c >> 3;                 // 0..255
            int jg = (c & 7) ^ (row & 7);
            async_copy16(A + (size_t)(m0 + row) * K + kt * 64 + jg * 8,
                         &As[buf][c * 8]);
        }
    };
    auto stageB = [&](int buf, int kt) {
#pragma unroll
        for (int i = 0; i < 3; ++i) {
            int c = tid + i * 512;            // 0..1535
            int row = c >> 3;                 // 0..191
            int jg = (c & 7) ^ (row & 7);
            async_copy16(B + (size_t)(n0 + row) * K + kt * 64 + jg * 8,
                         &Bs[buf][c * 8]);
        }
    };

    stageA(0, 0);
    stageB(0, 0);
    asm volatile("s_waitcnt vmcnt(0)");
    asm volatile("" ::: "memory");
    __builtin_amdgcn_s_barrier();

    for (int t = 0; t < GTILES; ++t) {
        const int cur = t & 1;
        const short* as = As[cur];
        const short* bs = Bs[cur];
        bf16x8 af[8], bfr[2];

        // ---- P1: A frags ks=0 (8 dsr) + B ni=0,1 ks=0 (2 dsr) | stage A(t+1)
#pragma unroll
        for (int mi = 0; mi < 8; ++mi) {
            int row = wr * 128 + mi * 16 + l15;
            af[mi] = *(const bf16x8*)&as[row * 64 + ((0 + quad) ^ (row & 7)) * 8];
        }
#pragma unroll
        for (int ni = 0; ni < 2; ++ni) {
            int row = wc * 48 + ni * 16 + l15;
            bfr[ni] = *(const bf16x8*)&bs[row * 64 + ((0 + quad) ^ (row & 7)) * 8];
        }
        if (t + 1 < GTILES) stageA(cur ^ 1, t + 1);
        asm volatile("" ::: "memory");
        __builtin_amdgcn_s_barrier();
        asm volatile("s_waitcnt lgkmcnt(0)");
        __builtin_amdgcn_s_setprio(1);
#pragma unroll
        for (int mi = 0; mi < 8; ++mi)
#pragma unroll
            for (int ni = 0; ni < 2; ++ni)
                acc[mi][ni] = __builtin_amdgcn_mfma_f32_16x16x32_bf16(af[mi], bfr[ni], acc[mi][ni], 0, 0, 0);
        __builtin_amdgcn_s_setprio(0);
        asm volatile("" ::: "memory");
        __builtin_amdgcn_s_barrier();

        // ---- P2: B ni=2 ks=0 (1 dsr) | stage B(t+1)
        {
            int row = wc * 48 + 2 * 16 + l15;
            bfr[0] = *(const bf16x8*)&bs[row * 64 + ((0 + quad) ^ (row & 7)) * 8];
        }
        if (t + 1 < GTILES) stageB(cur ^ 1, t + 1);
        asm volatile("" ::: "memory");
        __builtin_amdgcn_s_barrier();
        asm volatile("s_waitcnt lgkmcnt(0)");
        __builtin_amdgcn_s_setprio(1);
#pragma unroll
        for (int mi = 0; mi < 8; ++mi)
            acc[mi][2] = __builtin_amdgcn_mfma_f32_16x16x32_bf16(af[mi], bfr[0], acc[mi][2], 0, 0, 0);
        __builtin_amdgcn_s_setprio(0);
        asm volatile("" ::: "memory");
        __builtin_amdgcn_s_barrier();

        // ---- P3: A frags ks=1 (8 dsr) + B ni=0,1 ks=1 (2 dsr)
#pragma unroll
        for (int mi = 0; mi < 8; ++mi) {
            int row = wr * 128 + mi * 16 + l15;
            af[mi] = *(const bf16x8*)&as[row * 64 + ((4 + quad) ^ (row & 7)) * 8];
        }
#pragma unroll
        for (int ni = 0; ni < 2; ++ni) {
            int row = wc * 48 + ni * 16 + l15;
            bfr[ni] = *(const bf16x8*)&bs[row * 64 + ((4 + quad) ^ (row & 7)) * 8];
        }
        asm volatile("" ::: "memory");
        __builtin_amdgcn_s_barrier();
        asm volatile("s_waitcnt lgkmcnt(0)");
        __builtin_amdgcn_s_setprio(1);
#pragma unroll
        for (int mi = 0; mi < 8; ++mi)
#pragma unroll
            for (int ni = 0; ni < 2; ++ni)
                acc[mi][ni] = __builtin_amdgcn_mfma_f32_16x16x32_bf16(af[mi], bfr[ni], acc[mi][ni], 0, 0, 0);
        __builtin_amdgcn_s_setprio(0);
        asm volatile("" ::: "memory");
        __builtin_amdgcn_s_barrier();

        // ---- P4: B ni=2 ks=1 (1 dsr) | vmcnt(0) drains stage(t+1)
        {
            int row = wc * 48 + 2 * 16 + l15;
            bfr[0] = *(const bf16x8*)&bs[row * 64 + ((4 + quad) ^ (row & 7)) * 8];
        }
        asm volatile("s_waitcnt vmcnt(0)");
        asm volatile("" ::: "memory");
        __builtin_amdgcn_s_barrier();
        asm volatile("s_waitcnt lgkmcnt(0)");
        __builtin_amdgcn_s_setprio(1);
#pragma unroll
        for (int mi = 0; mi < 8; ++mi)
            acc[mi][2] = __builtin_amdgcn_mfma_f32_16x16x32_bf16(af[mi], bfr[0], acc[mi][2], 0, 0, 0);
        __builtin_amdgcn_s_setprio(0);
        asm volatile("" ::: "memory");
        __builtin_amdgcn_s_barrier();
    }

#pragma unroll
    for (int mi = 0; mi < 8; ++mi)
#pragma unroll
        for (int ni = 0; ni < 3; ++ni)
#pragma unroll
            for (int r = 0; r < 4; ++r)
                C[(size_t)(m0 + wr * 128 + mi * 16 + quad * 4 + r) * N +
                  n0 + wc * 48 + ni * 16 + l15] = f2bf(acc[mi][ni][r]);
}

// ---------------- 2b. MFMA GEMM 128x64 (fp32 out) — stage-ahead dbuf ----------
// r2-proven schedule applied to the out-projection: stage(t+1) into the spare
// LDS buffer BEFORE compute(t); ONE barrier per K-tile (its implicit
// vmcnt(0) drain waits on loads that aged through 16 MFMAs) — replaces the
// old 2-drains-per-K-step structure (m233: that stall ~72% of a 2-phase
// loop). LDS 48KB dbuf -> 3 blocks/CU; race-free: writes always target
// buf[cur^1], end-of-iter barrier separates reads from next writes.
__global__ __launch_bounds__(256) void gemm_bt_mfma_n64(const unsigned short* __restrict__ A,
                                                        const unsigned short* __restrict__ B,
                                                        float* __restrict__ C,
                                                        int M, int N, int K) {
    __shared__ short As[2][128 * 64];
    __shared__ short Bs[2][64 * 64];
    const int tid = threadIdx.x;
    const int w = tid >> 6, lane = tid & 63, quad = lane >> 4, l15 = lane & 15;
    int id = blockIdx.y * 16 + blockIdx.x;   // grid (16, 32) -> 512 blocks
    id = (id & 7) * 64 + (id >> 3);          // XCD-bijective (512 % 8 == 0)
    const int m0 = (id >> 4) * 128, n0 = (id & 15) * 64;
    const int wm = (w & 1) * 64, wn = (w >> 1) * 32;
    f32x4 acc[4][2];
#pragma unroll
    for (int i = 0; i < 4; ++i)
#pragma unroll
        for (int j = 0; j < 2; ++j) acc[i][j] = f32x4{0.f, 0.f, 0.f, 0.f};

    auto stage = [&](int buf, int kt) {
#pragma unroll
        for (int j = 0; j < 4; ++j) {
            int c = tid + j * 256;
            int row = c >> 3;
            int jg = (c & 7) ^ (row & 7);
            async_copy16(A + (size_t)(m0 + row) * K + kt * 64 + jg * 8,
                         &As[buf][c * 8]);
        }
#pragma unroll
        for (int j = 0; j < 2; ++j) {
            int c = tid + j * 256;
            int row = c >> 3;
            int jg = (c & 7) ^ (row & 7);
            async_copy16(B + (size_t)(n0 + row) * K + kt * 64 + jg * 8,
                         &Bs[buf][c * 8]);
        }
    };

    const int NT = K / 64;          // 16
    stage(0, 0);
    __syncthreads();                 // drains stage(0)

    for (int t = 0; t < NT; ++t) {
        const int cur = t & 1;
        if (t + 1 < NT) stage(cur ^ 1, t + 1);   // prefetch next tile, no wait
#pragma unroll
        for (int ks = 0; ks < 2; ++ks) {
            bf16x8 a[4], b[2];
#pragma unroll
            for (int mi = 0; mi < 4; ++mi) {
                int row = wm + mi * 16 + l15;
                int ch = (ks * 4 + quad) ^ (row & 7);
                a[mi] = *(const bf16x8*)&As[cur][row * 64 + ch * 8];
            }
#pragma unroll
            for (int ni = 0; ni < 2; ++ni) {
                int row = wn + ni * 16 + l15;
                int ch = (ks * 4 + quad) ^ (row & 7);
                b[ni] = *(const bf16x8*)&Bs[cur][row * 64 + ch * 8];
            }
#pragma unroll
            for (int mi = 0; mi < 4; ++mi)
#pragma unroll
                for (int ni = 0; ni < 2; ++ni)
                    acc[mi][ni] = __builtin_amdgcn_mfma_f32_16x16x32_bf16(a[mi], b[ni], acc[mi][ni], 0, 0, 0);
        }
        // single barrier per K-tile: all waves done reading buf[cur] AND the
        // prefetch DMA into buf[cur^1] drained (aged through compute).
        __syncthreads();
    }
#pragma unroll
    for (int mi = 0; mi < 4; ++mi)
#pragma unroll
        for (int ni = 0; ni < 2; ++ni)
#pragma unroll
            for (int r = 0; r < 4; ++r)
                C[(size_t)(m0 + wm + mi * 16 + quad * 4 + r) * N + n0 + wn + ni * 16 + l15] =
                    acc[mi][ni][r];
}

// ---------------- 3. fused Q/K finalize (wave-per-row) + V transpose ----------
__global__ __launch_bounds__(256) void qkv_final_kernel(const unsigned short* __restrict__ qkvb,
                                                        const float* __restrict__ qlnw,
                                                        const float* __restrict__ klnw,
                                                        const float* __restrict__ ropec,
                                                        const float* __restrict__ ropes,
                                                        unsigned short* __restrict__ qt,
                                                        unsigned short* __restrict__ kt,
                                                        unsigned short* __restrict__ vtt) {
    const int blk = blockIdx.x;
    const int tid = threadIdx.x;
    if (blk < BL / 4) {
        const int w64 = tid >> 6;
        const int L = tid & 63;
        const int row = blk * 4 + w64;
        const int b = row >> 11;
        const int l = row & (Ls - 1);
        const unsigned short* qp = qkvb + (size_t)row * (3 * Dd);
        const unsigned short* kp = qp + Dd;

        bf16x8 qA = *(const bf16x8*)(qp + L * 8);
        bf16x8 qB = *(const bf16x8*)(qp + 512 + L * 8);
        bf16x8 kA = *(const bf16x8*)(kp + L * 8);
        bf16x8 kB = *(const bf16x8*)(kp + 512 + L * 8);
        float vq[16], vk[16];
#pragma unroll
        for (int j = 0; j < 8; ++j) {
            vq[j] = bf2f((unsigned short)qA[j]);
            vq[8 + j] = bf2f((unsigned short)qB[j]);
            vk[j] = bf2f((unsigned short)kA[j]);
            vk[8 + j] = bf2f((unsigned short)kB[j]);
        }
        float sq = 0.f, sk = 0.f;
#pragma unroll
        for (int j = 0; j < 16; ++j) { sq += vq[j]; sk += vk[j]; }
#pragma unroll
        for (int off = 1; off < 64; off <<= 1) {
            sq += __shfl_xor(sq, off, 64);
            sk += __shfl_xor(sk, off, 64);
        }
        float mq = sq * (1.0f / Dd), mk = sk * (1.0f / Dd);
        float vvq = 0.f, vvk = 0.f;
#pragma unroll
        for (int j = 0; j < 16; ++j) {
            vq[j] -= mq; vvq += vq[j] * vq[j];
            vk[j] -= mk; vvk += vk[j] * vk[j];
        }
#pragma unroll
        for (int off = 1; off < 64; off <<= 1) {
            vvq += __shfl_xor(vvq, off, 64);
            vvk += __shfl_xor(vvk, off, 64);
        }
        float rsq = rsqrtf(vvq * (1.0f / Dd) + LN_EPS);
        float rsk = rsqrtf(vvk * (1.0f / Dd) + LN_EPS);

        float yq[16], yk[16];
        {
            float4 w0 = *(const float4*)(qlnw + L * 8);
            float4 w1 = *(const float4*)(qlnw + L * 8 + 4);
            float4 w2 = *(const float4*)(qlnw + 512 + L * 8);
            float4 w3 = *(const float4*)(qlnw + 512 + L * 8 + 4);
            yq[0] = vq[0] * rsq * w0.x; yq[1] = vq[1] * rsq * w0.y;
            yq[2] = vq[2] * rsq * w0.z; yq[3] = vq[3] * rsq * w0.w;
            yq[4] = vq[4] * rsq * w1.x; yq[5] = vq[5] * rsq * w1.y;
            yq[6] = vq[6] * rsq * w1.z; yq[7] = vq[7] * rsq * w1.w;
            yq[8] = vq[8] * rsq * w2.x; yq[9] = vq[9] * rsq * w2.y;
            yq[10] = vq[10] * rsq * w2.z; yq[11] = vq[11] * rsq * w2.w;
            yq[12] = vq[12] * rsq * w3.x; yq[13] = vq[13] * rsq * w3.y;
            yq[14] = vq[14] * rsq * w3.z; yq[15] = vq[15] * rsq * w3.w;
        }
        {
            float4 w0 = *(const float4*)(klnw + L * 8);
            float4 w1 = *(const float4*)(klnw + L * 8 + 4);
            float4 w2 = *(const float4*)(klnw + 512 + L * 8);
            float4 w3 = *(const float4*)(klnw + 512 + L * 8 + 4);
            yk[0] = vk[0] * rsk * w0.x; yk[1] = vk[1] * rsk * w0.y;
            yk[2] = vk[2] * rsk * w0.z; yk[3] = vk[3] * rsk * w0.w;
            yk[4] = vk[4] * rsk * w1.x; yk[5] = vk[5] * rsk * w1.y;
            yk[6] = vk[6] * rsk * w1.z; yk[7] = vk[7] * rsk * w1.w;
            yk[8] = vk[8] * rsk * w2.x; yk[9] = vk[9] * rsk * w2.y;
            yk[10] = vk[10] * rsk * w2.z; yk[11] = vk[11] * rsk * w2.w;
            yk[12] = vk[12] * rsk * w3.x; yk[13] = vk[13] * rsk * w3.y;
            yk[14] = vk[14] * rsk * w3.z; yk[15] = vk[15] * rsk * w3.w;
        }

        float cs[8], sn[8];
        {
            int fbase = l * 32 + (L & 3) * 8;
            float4 c0 = *(const float4*)(ropec + fbase);
            float4 c1 = *(const float4*)(ropec + fbase + 4);
            float4 s0 = *(const float4*)(ropes + fbase);
            float4 s1 = *(const float4*)(ropes + fbase + 4);
            cs[0] = c0.x; cs[1] = c0.y; cs[2] = c0.z; cs[3] = c0.w;
            cs[4] = c1.x; cs[5] = c1.y; cs[6] = c1.z; cs[7] = c1.w;
            sn[0] = s0.x; sn[1] = s0.y; sn[2] = s0.z; sn[3] = s0.w;
            sn[4] = s1.x; sn[5] = s1.y; sn[6] = s1.z; sn[7] = s1.w;
        }
        const float sgn = (L & 4) ? 1.0f : -1.0f;  // dh>=32 ? + : -
        unsigned short outqA[8], outqB[8], outkA[8], outkB[8];
#pragma unroll
        for (int j = 0; j < 8; ++j) {
            float pA = __shfl_xor(yq[j], 4, 64);
            float pB = __shfl_xor(yq[8 + j], 4, 64);
            outqA[j] = f2bf((yq[j] * cs[j] + sgn * pA * sn[j]) * QSCL);
            outqB[j] = f2bf((yq[8 + j] * cs[j] + sgn * pB * sn[j]) * QSCL);
            float pkA = __shfl_xor(yk[j], 4, 64);
            float pkB = __shfl_xor(yk[8 + j], 4, 64);
            outkA[j] = f2bf(yk[j] * cs[j] + sgn * pkA * sn[j]);
            outkB[j] = f2bf(yk[8 + j] * cs[j] + sgn * pkB * sn[j]);
        }
        const int hA = L >> 3;
        const int dh0 = (L & 7) * 8;
        size_t offA = (((size_t)(b * Hh + hA)) * Ls + l) * DHh + dh0;
        size_t offB = (((size_t)(b * Hh + 8 + hA)) * Ls + l) * DHh + dh0;
        *(uint4*)(qt + offA) = *(uint4*)outqA;
        *(uint4*)(qt + offB) = *(uint4*)outqB;
        *(uint4*)(kt + offA) = *(uint4*)outkA;
        *(uint4*)(kt + offB) = *(uint4*)outkB;
    } else {
        // ---- V transpose tile ----
        const int t2 = blk - BL / 4;           // 0..1023
        const int l0 = (t2 & 31) * 64;
        const int h = (t2 >> 5) & 15;
        const int b = t2 >> 9;
        __shared__ short t[64][72];
        const unsigned short* src = qkvb + (size_t)b * Ls * (3 * Dd) + 2 * Dd + h * 64;
#pragma unroll
        for (int j = 0; j < 2; ++j) {
            int g = tid + j * 256;
            int row = g >> 3;
            int c0 = (g & 7) * 8;
            uint4 vv = *(const uint4*)(src + (size_t)(l0 + row) * (3 * Dd) + c0);
            *(uint4*)&t[row][c0] = vv;
        }
        __syncthreads();
        unsigned short* dst = vtt + ((size_t)(b * Hh + h) * DHh) * Ls;
#pragma unroll
        for (int j = 0; j < 2; ++j) {
            int g = tid + j * 256;
            int dh = g >> 3;
            int lc = (g & 7) * 8;
            ushort4 o0, o1;
            unsigned short* p0 = (unsigned short*)&o0;
            unsigned short* p1 = (unsigned short*)&o1;
#pragma unroll
            for (int i = 0; i < 4; ++i) p0[i] = (unsigned short)t[lc + i][dh];
#pragma unroll
            for (int i = 0; i < 4; ++i) p1[i] = (unsigned short)t[lc + 4 + i][dh];
            *(ushort4*)(dst + (size_t)dh * Ls + l0 + lc) = o0;
            *(ushort4*)(dst + (size_t)dh * Ls + l0 + lc + 4) = o1;
        }
    }
}

// ---------------- 5. MFMA flash attention — Q=128, 8 waves, dbuf pipeline ----
// (round-3 configuration: session-best attn)
constexpr int PSP = 76;  // Ps pitch (bank-conflict-free, measured 0 conflicts)

__global__ __launch_bounds__(512) void attn_kernel(const unsigned short* __restrict__ qt,
                                                   const unsigned short* __restrict__ kt,
                                                   const unsigned short* __restrict__ vtt,
                                                   const int* __restrict__ seq_id,
                                                   unsigned short* __restrict__ ctxb) {
    const int id = blockIdx.x;            // 0..511
    const int c8 = id & 7;                // XCD-swizzle: h%8 pinned per XCD
    const int x = (id >> 3) & 15;
    const int g4 = id >> 7;               // 0..3
    const int v = c8 + 8 * g4;            // h + 16*b
    const int b = v >> 4;
    const int h = v & 15;
    const int q0 = x * 128;

    const size_t base = ((size_t)(b * Hh + h)) * Ls * DHh;
    const size_t base_v = ((size_t)(b * Hh + h)) * DHh * Ls;
    const int* sid = seq_id + (size_t)b * Ls;

    __shared__ short Ks[2][64 * 64];
    __shared__ short Vs[2][64 * 64];
    __shared__ short Ps[8][16 * PSP];
    __shared__ int sq_s[128];

    const int tid = threadIdx.x;
    const int w = tid >> 6;               // 0..7
    const int lane = tid & 63;
    const int quad = lane >> 4;
    const int l15 = lane & 15;

    if (tid < 128) sq_s[tid] = sid[q0 + tid];
    const int qmin = sid[q0];
    const int qmax = sid[q0 + 127];

    // prune K-tiles outside this Q-tile's segment range (sid sorted)
    bool need = false;
    if (lane < 32) {
        int kmn = sid[lane * 64];
        int kmx = sid[lane * 64 + 63];
        need = (kmn <= qmax) && (kmx >= qmin);
    }
    unsigned long long bmask = __ballot(need);
    const int t0 = __builtin_ctzll(bmask);
    const int t1 = 64 - __builtin_clzll(bmask);

    // stage K/V tile t into buffer buf: 512 threads x 16B = one full 8KB tile
    // each for K and V (swizzled global source -> linear LDS dest).
    auto stage = [&](int buf, int t) {
        int row = tid >> 3;                    // 0..63
        int jg = (tid & 7) ^ (row & 7);
        async_copy16(kt + base + (size_t)(t * 64 + row) * DHh + jg * 8,
                     &Ks[buf][tid * 8]);
        async_copy16(vtt + base_v + (size_t)row * Ls + t * 64 + jg * 8,
                     &Vs[buf][tid * 8]);
    };

    stage(0, t0);
    const int qrow = q0 + w * 16 + l15;
    const bf16x8 a0 = *(const bf16x8*)(qt + base + (size_t)qrow * DHh + quad * 8);
    const bf16x8 a1 = *(const bf16x8*)(qt + base + (size_t)qrow * DHh + 32 + quad * 8);

    int sqv[4];
    float lsum[4] = {0.f, 0.f, 0.f, 0.f};
    f32x4 O[4];
#pragma unroll
    for (int r = 0; r < 4; ++r) O[r] = f32x4{0.f, 0.f, 0.f, 0.f};

    __syncthreads();   // drains stage(t0) + publishes sq_s
#pragma unroll
    for (int r = 0; r < 4; ++r) sqv[r] = sq_s[w * 16 + quad * 4 + r];

    for (int t = t0; t < t1; ++t) {
        const int cur = (t - t0) & 1;
        if (t + 1 < t1) stage(cur ^ 1, t + 1);   // prefetch next tile, no wait
        const int k0 = t * 64;

        // QK^T from Ks[cur]
        f32x4 s[4];
#pragma unroll
        for (int kg = 0; kg < 4; ++kg) {
            int krow = kg * 16 + l15;
            bf16x8 b0 = *(const bf16x8*)&Ks[cur][krow * 64 + ((0 + quad) ^ (krow & 7)) * 8];
            bf16x8 b1 = *(const bf16x8*)&Ks[cur][krow * 64 + ((4 + quad) ^ (krow & 7)) * 8];
            f32x4 acc = {0.f, 0.f, 0.f, 0.f};
            acc = __builtin_amdgcn_mfma_f32_16x16x32_bf16(a0, b0, acc, 0, 0, 0);
            acc = __builtin_amdgcn_mfma_f32_16x16x32_bf16(a1, b1, acc, 0, 0, 0);
            s[kg] = acc;
        }

        const int kmn = sid[k0];
        const int kmx = sid[k0 + 63];
        const bool nomask = (kmn == kmx) && (qmin == qmax) && (kmn == qmin);
        if (!nomask) {
#pragma unroll
            for (int kg = 0; kg < 4; ++kg) {
                int skv = sid[k0 + kg * 16 + l15];
#pragma unroll
                for (int r = 0; r < 4; ++r)
                    if (sqv[r] != skv) s[kg][r] = -3.0e38f;
            }
        }
#pragma unroll
        for (int kg = 0; kg < 4; ++kg)
#pragma unroll
            for (int r = 0; r < 4; ++r)
                s[kg][r] = __builtin_amdgcn_exp2f(s[kg][r]);
#pragma unroll
        for (int r = 0; r < 4; ++r)
            lsum[r] += s[0][r] + s[1][r] + s[2][r] + s[3][r];

        // P -> per-wave LDS (layout transform for PV A-fragment); no barrier:
        // DS pipe is in-order within a wave, compiler inserts lgkmcnt waits.
#pragma unroll
        for (int kg = 0; kg < 4; ++kg)
#pragma unroll
            for (int r = 0; r < 4; ++r)
                Ps[w][(quad * 4 + r) * PSP + kg * 16 + l15] = (short)f2bf(s[kg][r]);

        bf16x8 pa0 = *(const bf16x8*)&Ps[w][l15 * PSP + quad * 8];
        bf16x8 pa1 = *(const bf16x8*)&Ps[w][l15 * PSP + 32 + quad * 8];
#pragma unroll
        for (int ng = 0; ng < 4; ++ng) {
            int vrow = ng * 16 + l15;
            bf16x8 vb0 = *(const bf16x8*)&Vs[cur][vrow * 64 + ((0 + quad) ^ (vrow & 7)) * 8];
            bf16x8 vb1 = *(const bf16x8*)&Vs[cur][vrow * 64 + ((4 + quad) ^ (vrow & 7)) * 8];
            O[ng] = __builtin_amdgcn_mfma_f32_16x16x32_bf16(pa0, vb0, O[ng], 0, 0, 0);
            O[ng] = __builtin_amdgcn_mfma_f32_16x16x32_bf16(pa1, vb1, O[ng], 0, 0, 0);
        }

        // single barrier per K-tile: all waves done reading buf[cur] AND the
        // prefetch DMA into buf[cur^1] drained (aged through compute).
        __syncthreads();
    }

    // row-sum reduce over the 16 l15 lanes (quad fixed = row identity)
#pragma unroll
    for (int off = 1; off < 16; off <<= 1)
#pragma unroll
        for (int r = 0; r < 4; ++r)
            lsum[r] += __shfl_xor(lsum[r], off, 64);
    float inv_l[4];
#pragma unroll
    for (int r = 0; r < 4; ++r) inv_l[r] = 1.0f / lsum[r];
#pragma unroll
    for (int ng = 0; ng < 4; ++ng)
#pragma unroll
        for (int r = 0; r < 4; ++r) {
            int q = q0 + w * 16 + quad * 4 + r;
            ctxb[((size_t)b * Ls + q) * Dd + h * DHh + ng * 16 + l15] =
                f2bf(O[ng][r] * inv_l[r]);
        }
}

// ---------------- launcher ----------------
extern "C" void kernel_launch(void* const* d_in, const int* in_sizes, int n_in,
                              void* d_out, int out_size, void* d_ws, size_t ws_size,
                              hipStream_t stream) {
    const float* x = (const float*)d_in[0];
    const int* seq_id = (const int*)d_in[1];
    const float* ln_w = (const float*)d_in[2];
    const float* ln_b = (const float*)d_in[3];
    const float* w_qkv = (const float*)d_in[4];
    const float* q_lora_a = (const float*)d_in[5];
    const float* q_lora_b = (const float*)d_in[6];
    const float* v_lora_a = (const float*)d_in[7];
    const float* v_lora_b = (const float*)d_in[8];
    const float* q_ln_w = (const float*)d_in[9];
    const float* k_ln_w = (const float*)d_in[10];
    const float* w_out = (const float*)d_in[11];
    float* out = (float*)d_out;

    const size_t SZ = (size_t)BL * Dd;        // 4M elements
    float* p = (float*)d_ws;
    float* ropec = p;          p += (size_t)Ls * 32;
    float* ropes = p;          p += (size_t)Ls * 32;
    unsigned short* ub = (unsigned short*)p;
    unsigned short* qkvb = ub; ub += 3 * SZ;  // bf16 [BL, 3D]
    unsigned short* hb = ub;   ub += SZ;      // bf16 [BL, D]
    unsigned short* qt = ub;   ub += SZ;      // bf16 [B,H,L,DH] (prescaled)
    unsigned short* kt = ub;   ub += SZ;
    unsigned short* vtt = ub;  ub += SZ;      // bf16 [B,H,DH,L]
    unsigned short* ctxb = ub; ub += SZ;      // bf16 [BL, D]
    unsigned short* wqkvb = ub; ub += (size_t)3 * Dd * Dd;
    unsigned short* woutb = ub; ub += (size_t)Dd * Dd;

    prep_ln_kernel<<<3072, 256, 0, stream>>>(
        w_qkv, q_lora_a, q_lora_b, v_lora_a, v_lora_b, w_out,
        x, ln_w, ln_b, wqkvb, woutb, ropec, ropes, hb);
    {
        dim3 g(3 * Dd / 192, BL / 256);   // 16 x 16 = 256 blocks (full CU cover)
        gemm_qkv_256<<<g, 512, 0, stream>>>(hb, wqkvb, qkvb, BL, 3 * Dd, Dd);
    }
    qkv_final_kernel<<<BL / 4 + 1024, 256, 0, stream>>>(qkvb, q_ln_w, k_ln_w,
                                                        ropec, ropes, qt, kt, vtt);
    attn_kernel<<<512, 512, 0, stream>>>(qt, kt, vtt, seq_id, ctxb);
    {
        dim3 g(Dd / 64, BL / 128);
        gemm_bt_mfma_n64<<<g, 256, 0, stream>>>(ctxb, woutb, out, BL, Dd, Dd);
    }
}